// Round 1
// baseline (3075.986 us; speedup 1.0000x reference)
//
#include <hip/hip_runtime.h>
#include <math.h>

namespace {
constexpr int BB = 4096;   // batch
constexpr int NN = 41;     // nodes
constexpr int DD = 271;    // features
constexpr long long MROWS = (long long)BB * NN;   // 167936
}

// ---------------------------------------------------------------------------
// K1: wavelet basis. One block per sample: L, T2, T3, power-iter lambda_max,
// Bessel coefficients, thresholded + row-L1-normalized W / Wi.
// ---------------------------------------------------------------------------
__global__ __launch_bounds__(256) void k_wavelet(const float* __restrict__ G,
                                                 float* __restrict__ Wo,
                                                 float* __restrict__ Wio)
{
    __shared__ float sG[NN][NN + 1];
    __shared__ float sL[NN][NN + 1];
    __shared__ float sT2[NN][NN + 1];
    __shared__ float sT3[NN][NN + 1];
    __shared__ float sdeg[NN], sdinv[NN], srs[NN];
    __shared__ float slam;

    const int b   = blockIdx.x;
    const int tid = threadIdx.x;
    const float* Gb = G + (size_t)b * NN * NN;

    for (int e = tid; e < NN * NN; e += 256) sG[e / NN][e % NN] = Gb[e];
    __syncthreads();

    if (tid < NN) {
        float s = 0.f;
        #pragma unroll
        for (int j = 0; j < NN; ++j) s += sG[tid][j];
        sdeg[tid]  = s;
        sdinv[tid] = 1.0f / (sqrtf(s) + 1e-6f);
    }
    __syncthreads();

    for (int e = tid; e < NN * NN; e += 256) {
        int i = e / NN, j = e % NN;
        float a = 0.5f * (sG[i][j] + sG[j][i]);
        float v = ((i == j) ? sdeg[i] : 0.0f) - a;
        sL[i][j] = sdinv[i] * sdinv[j] * v;
    }
    __syncthreads();

    for (int e = tid; e < NN * NN; e += 256) {
        int i = e / NN, j = e % NN;
        float acc = 0.f;
        for (int k = 0; k < NN; ++k) acc += sL[i][k] * sL[k][j];
        sT2[i][j] = 2.0f * acc;
    }
    __syncthreads();

    for (int e = tid; e < NN * NN; e += 256) {
        int i = e / NN, j = e % NN;
        float acc = 0.f;
        for (int k = 0; k < NN; ++k) acc += sL[i][k] * sT2[k][j];
        sT3[i][j] = 2.0f * acc - sL[i][j];
    }
    __syncthreads();

    // power iteration (wave 0 only): lambda_max(L); L ~ PSD so max|eig|=lam_max
    if (tid < 64) {
        float lr[NN];
        #pragma unroll
        for (int j = 0; j < NN; ++j) lr[j] = (tid < NN) ? sL[tid][j] : 0.0f;
        float lam_best = 0.f;
        #pragma unroll
        for (int trial = 0; trial < 2; ++trial) {
            unsigned h = (unsigned)(tid + 1) * 2654435761u ^ (trial ? 0x9e3779b9u : 0u);
            h ^= h >> 13; h *= 0x85ebca6bu; h ^= h >> 16;
            float v = (tid < NN) ? (0.25f + (float)(h & 1023) * (1.0f / 1024.0f)) : 0.0f;
            float lam = 0.f;
            for (int it = 0; it < 150; ++it) {
                float acc = 0.f;
                #pragma unroll
                for (int j = 0; j < NN; ++j) {
                    float vj = __shfl(v, j, 64);
                    acc += lr[j] * vj;
                }
                float n2 = acc * acc;
                #pragma unroll
                for (int off = 32; off > 0; off >>= 1) n2 += __shfl_xor(n2, off, 64);
                lam = sqrtf(n2);
                v = acc * ((lam > 0.f) ? (1.0f / lam) : 0.0f);
            }
            lam_best = fmaxf(lam_best, lam);
        }
        if (tid == 0) slam = lam_best;
    }
    __syncthreads();

    const float x = 0.15f * slam;            // S * 0.5 * lam, S = 0.3
    float iv[4];
    {
        const float xh = 0.5f * x, xh2 = xh * xh;
        #pragma unroll
        for (int n = 0; n < 4; ++n) {
            float c = 1.0f;                  // 1/n!
            for (int q = 2; q <= n; ++q) c /= (float)q;
            float p = 1.0f;                  // xh^n
            for (int q = 0; q < n; ++q) p *= xh;
            float s = 0.f;
            for (int k = 0; k < 25; ++k) {
                s += c * p;
                p *= xh2;
                c /= (float)((k + 1) * (k + 1 + n));
            }
            iv[n] = s;
        }
    }
    const float ex = expf(x), emx = expf(-x);
    // pass 0: W coeffs (2 e^x I_n);  pass 1: Wi coeffs (2 e^-x I_n (-1)^n)
    #pragma unroll
    for (int pass = 0; pass < 2; ++pass) {
        const float a1 = pass ? (-2.f * emx * iv[1]) : (2.f * ex * iv[1]);
        const float a2 = pass ? ( 2.f * emx * iv[2]) : (2.f * ex * iv[2]);
        const float a3 = pass ? (-2.f * emx * iv[3]) : (2.f * ex * iv[3]);
        for (int e = tid; e < NN * NN; e += 256) {
            int i = e / NN, j = e % NN;
            float w = a1 * sL[i][j] + a2 * sT2[i][j] + a3 * sT3[i][j];
            sG[i][j] = (w < 1e-4f) ? 0.0f : w;   // threshold BEFORE l1norm
        }
        __syncthreads();
        if (tid < NN) {
            float s = 0.f;
            #pragma unroll
            for (int j = 0; j < NN; ++j) s += fabsf(sG[tid][j]);
            srs[tid] = 1.0f / fmaxf(s, 1e-12f);
        }
        __syncthreads();
        float* dst = (pass ? Wio : Wo) + (size_t)b * NN * NN;
        for (int e = tid; e < NN * NN; e += 256) dst[e] = sG[e / NN][e % NN] * srs[e / NN];
        __syncthreads();
    }
}

// ---------------------------------------------------------------------------
// K2/K4: generic f32 GEMM  C[M,271] = act(A[M,271] @ Bm[271,271] + bias)
// 64x64 tile, 256 threads, 4x4 micro-tile, K-tile 16. M divisible by 64.
// ---------------------------------------------------------------------------
__global__ __launch_bounds__(256) void k_gemm271(const float* __restrict__ A,
                                                 const float* __restrict__ Bm,
                                                 const float* __restrict__ bias,
                                                 float* __restrict__ C,
                                                 const int relu)
{
    __shared__ float As[16][68];   // [k][m], row stride 272B (16B aligned)
    __shared__ float Bs[16][68];   // [k][n]
    const int tid = threadIdx.x;
    const int tx = tid & 15, ty = tid >> 4;
    const long long row0 = (long long)blockIdx.x * 64;
    const int col0 = blockIdx.y * 64;
    float acc[4][4] = {};

    for (int kt = 0; kt < DD; kt += 16) {
        for (int l = tid; l < 64 * 16; l += 256) {
            int m = l >> 4, k = l & 15;
            int kk = kt + k;
            As[k][m] = (kk < DD) ? A[(row0 + m) * DD + kk] : 0.0f;
        }
        for (int l = tid; l < 16 * 64; l += 256) {
            int k = l >> 6, n = l & 63;
            int kk = kt + k, cn = col0 + n;
            Bs[k][n] = (kk < DD && cn < DD) ? Bm[(size_t)kk * DD + cn] : 0.0f;
        }
        __syncthreads();
        #pragma unroll
        for (int k = 0; k < 16; ++k) {
            const float4 a4 = *reinterpret_cast<const float4*>(&As[k][ty * 4]);
            const float4 b4 = *reinterpret_cast<const float4*>(&Bs[k][tx * 4]);
            const float av[4] = {a4.x, a4.y, a4.z, a4.w};
            const float bv[4] = {b4.x, b4.y, b4.z, b4.w};
            #pragma unroll
            for (int r = 0; r < 4; ++r)
                #pragma unroll
                for (int c = 0; c < 4; ++c)
                    acc[r][c] = fmaf(av[r], bv[c], acc[r][c]);
        }
        __syncthreads();
    }
    #pragma unroll
    for (int r = 0; r < 4; ++r) {
        const long long row = row0 + ty * 4 + r;
        #pragma unroll
        for (int c = 0; c < 4; ++c) {
            const int col = col0 + tx * 4 + c;
            if (col < DD) {
                float v = acc[r][c] + (bias ? bias[col] : 0.0f);
                if (relu) v = fmaxf(v, 0.0f);
                C[row * DD + col] = v;
            }
        }
    }
}

// ---------------------------------------------------------------------------
// K3: per-sample wavelet application, in-place on h:
//   h <- exp(lsv) * relu( W @ (gk .* (Wi @ h)) )
// grid = (B, 4 column chunks of 68). LDS transposed chunk for float4 j-loops.
// ---------------------------------------------------------------------------
__global__ __launch_bounds__(256) void k_wavapply(const float* __restrict__ Wwav,
                                                  const float* __restrict__ Wiwav,
                                                  const float* __restrict__ gk,
                                                  const float* __restrict__ lsv,
                                                  float* __restrict__ h)
{
    constexpr int CW = 68;   // chunk width
    constexpr int PS = 60;   // padded stride (240B = 15*16, conflict-free b128)
    constexpr int PW = 44;   // padded W stride (176B)
    __shared__ float sWi[NN][PW];
    __shared__ float sW[NN][PW];
    __shared__ float shT[CW][PS];
    __shared__ float stT[CW][PS];
    __shared__ float sgk[NN];

    const int b   = blockIdx.x;
    const int c0  = blockIdx.y * CW;
    const int tid = threadIdx.x;
    const float* Wb  = Wwav  + (size_t)b * NN * NN;
    const float* Wib = Wiwav + (size_t)b * NN * NN;

    for (int e = tid; e < NN * PW; e += 256) {
        int i = e / PW, j = e % PW;
        float wv = 0.f, wiv = 0.f;
        if (j < NN) { wv = Wb[i * NN + j]; wiv = Wib[i * NN + j]; }
        sW[i][j] = wv; sWi[i][j] = wiv;
    }
    if (tid < NN) sgk[tid] = gk[tid];
    for (int e = tid; e < NN * CW; e += 256) {
        int i = e / CW, c = e % CW;
        int cc = c0 + c;
        shT[c][i] = (cc < DD) ? h[((size_t)b * NN + i) * DD + cc] : 0.0f;
    }
    for (int e = tid; e < CW * 3; e += 256) {       // zero j = 41..43 pads
        int c = e / 3, j = NN + (e % 3);
        shT[c][j] = 0.f; stT[c][j] = 0.f;
    }
    __syncthreads();

    for (int e = tid; e < NN * CW; e += 256) {
        int i = e / CW, c = e % CW;
        float acc = 0.f;
        #pragma unroll
        for (int q = 0; q < 11; ++q) {
            const float4 w4 = *reinterpret_cast<const float4*>(&sWi[i][q * 4]);
            const float4 h4 = *reinterpret_cast<const float4*>(&shT[c][q * 4]);
            acc = fmaf(w4.x, h4.x, acc); acc = fmaf(w4.y, h4.y, acc);
            acc = fmaf(w4.z, h4.z, acc); acc = fmaf(w4.w, h4.w, acc);
        }
        stT[c][i] = sgk[i] * acc;
    }
    __syncthreads();

    for (int e = tid; e < NN * CW; e += 256) {
        int i = e / CW, c = e % CW;
        int cc = c0 + c;
        if (cc < DD) {
            float acc = 0.f;
            #pragma unroll
            for (int q = 0; q < 11; ++q) {
                const float4 w4 = *reinterpret_cast<const float4*>(&sW[i][q * 4]);
                const float4 t4 = *reinterpret_cast<const float4*>(&stT[c][q * 4]);
                acc = fmaf(w4.x, t4.x, acc); acc = fmaf(w4.y, t4.y, acc);
                acc = fmaf(w4.z, t4.z, acc); acc = fmaf(w4.w, t4.w, acc);
            }
            acc = fmaxf(acc, 0.0f) * expf(lsv[i * DD + cc]);
            h[((size_t)b * NN + i) * DD + cc] = acc;
        }
    }
}

// ---------------------------------------------------------------------------
// K5: mean over nodes
// ---------------------------------------------------------------------------
__global__ __launch_bounds__(256) void k_mean(const float* __restrict__ fr, float* __restrict__ seq)
{
    const int b = blockIdx.x;
    for (int d = threadIdx.x; d < DD; d += 256) {
        float s = 0.f;
        #pragma unroll
        for (int n = 0; n < NN; ++n) s += fr[((size_t)b * NN + n) * DD + d];
        seq[(size_t)b * DD + d] = s * (1.0f / 41.0f);
    }
}

// ---------------------------------------------------------------------------
// K6: per-feature BN stats (deterministic column reduction)
// ---------------------------------------------------------------------------
__global__ __launch_bounds__(256) void k_stats(const float* __restrict__ seq, float* __restrict__ stats)
{
    __shared__ float s1[256], s2[256];
    const int d = blockIdx.x;
    float a = 0.f, q = 0.f;
    for (int b = threadIdx.x; b < BB; b += 256) {
        float v = seq[(size_t)b * DD + d];
        a += v; q = fmaf(v, v, q);
    }
    s1[threadIdx.x] = a; s2[threadIdx.x] = q;
    __syncthreads();
    for (int o = 128; o > 0; o >>= 1) {
        if (threadIdx.x < o) { s1[threadIdx.x] += s1[threadIdx.x + o]; s2[threadIdx.x] += s2[threadIdx.x + o]; }
        __syncthreads();
    }
    if (threadIdx.x == 0) {
        float m = s1[0] * (1.0f / BB);
        float v = s2[0] * (1.0f / BB) - m * m;
        stats[d]      = m;
        stats[DD + d] = 1.0f / sqrtf(v + 1e-5f);
    }
}

// ---------------------------------------------------------------------------
// K7: apply BN
// ---------------------------------------------------------------------------
__global__ __launch_bounds__(256) void k_bn(const float* __restrict__ seq, const float* __restrict__ stats,
                                            const float* __restrict__ g, const float* __restrict__ bt,
                                            float* __restrict__ out)
{
    const long long idx = (long long)blockIdx.x * 256 + threadIdx.x;
    if (idx < (long long)BB * DD) {
        const int d = (int)(idx % DD);
        out[idx] = (seq[idx] - stats[d]) * stats[DD + d] * g[d] + bt[d];
    }
}

// ---------------------------------------------------------------------------
extern "C" void kernel_launch(void* const* d_in, const int* in_sizes, int n_in,
                              void* d_out, int out_size, void* d_ws, size_t ws_size,
                              hipStream_t stream)
{
    const float* G   = (const float*)d_in[0];
    const float* X   = (const float*)d_in[1];
    const float* gk  = (const float*)d_in[2];
    const float* gW  = (const float*)d_in[3];
    const float* lsv = (const float*)d_in[4];
    const float* W1  = (const float*)d_in[5];
    const float* b1  = (const float*)d_in[6];
    const float* W2  = (const float*)d_in[7];
    const float* b2  = (const float*)d_in[8];
    const float* gam = (const float*)d_in[9];
    const float* bet = (const float*)d_in[10];

    float* ws = (float*)d_ws;
    size_t off = 0;
    float* Wwav  = ws + off; off += (size_t)BB * NN * NN;   // 27.5 MB
    float* Wiwav = ws + off; off += (size_t)BB * NN * NN;   // 27.5 MB
    float* bufA  = ws + off; off += (size_t)BB * NN * DD;   // 182 MB
    float* bufB  = ws + off; off += (size_t)BB * NN * DD;   // 182 MB
    float* seq   = ws + off; off += (size_t)BB * DD;        // 4.4 MB
    float* stats = ws + off; off += 2 * DD;

    k_wavelet<<<BB, 256, 0, stream>>>(G, Wwav, Wiwav);
    k_gemm271<<<dim3((unsigned)(MROWS / 64), 5), 256, 0, stream>>>(X, gW, nullptr, bufA, 0);
    k_wavapply<<<dim3(BB, 4), 256, 0, stream>>>(Wwav, Wiwav, gk, lsv, bufA);
    k_gemm271<<<dim3((unsigned)(MROWS / 64), 5), 256, 0, stream>>>(bufA, W1, b1, bufB, 1);
    k_gemm271<<<dim3((unsigned)(MROWS / 64), 5), 256, 0, stream>>>(bufB, W2, b2, bufA, 0);
    k_mean<<<BB, 256, 0, stream>>>(bufA, seq);
    k_stats<<<DD, 256, 0, stream>>>(seq, stats);
    k_bn<<<(unsigned)(((long long)BB * DD + 255) / 256), 256, 0, stream>>>(seq, stats, gam, bet, (float*)d_out);
}

// Round 2
// 2145.324 us; speedup vs baseline: 1.4338x; 1.4338x over previous
//
#include <hip/hip_runtime.h>
#include <math.h>

namespace {
constexpr int BB = 4096;   // batch
constexpr int NN = 41;     // nodes
constexpr int DD = 271;    // features
constexpr int PW = 44;     // padded row stride for 41-wide LDS matrices (176B, 16B-aligned)
constexpr long long MROWS = (long long)BB * NN;   // 167936
}

// ---------------------------------------------------------------------------
// LDS matmul helper: C = scale * A@B - (sub ? sub : 0), 41x41, stride-44 rows,
// pad columns (41..43) of A/B assumed zero -> C pads come out zero.
// 451 float4 strips over 256 threads. Caller handles __syncthreads().
// ---------------------------------------------------------------------------
__device__ __forceinline__ void lds_mm(const float (*__restrict__ A)[PW],
                                       const float (*__restrict__ B)[PW],
                                       float (*__restrict__ C)[PW],
                                       const float scale,
                                       const float (*__restrict__ sub)[PW],
                                       const int tid)
{
    for (int s = tid; s < NN * 11; s += 256) {
        const int i = s / 11, q = s % 11;
        float4 acc = make_float4(0.f, 0.f, 0.f, 0.f);
        #pragma unroll
        for (int k = 0; k < NN; ++k) {
            const float a = A[i][k];
            const float4 b4 = *reinterpret_cast<const float4*>(&B[k][q * 4]);
            acc.x = fmaf(a, b4.x, acc.x); acc.y = fmaf(a, b4.y, acc.y);
            acc.z = fmaf(a, b4.z, acc.z); acc.w = fmaf(a, b4.w, acc.w);
        }
        float4 r;
        if (sub) {
            const float4 s4 = *reinterpret_cast<const float4*>(&sub[i][q * 4]);
            r = make_float4(fmaf(scale, acc.x, -s4.x), fmaf(scale, acc.y, -s4.y),
                            fmaf(scale, acc.z, -s4.z), fmaf(scale, acc.w, -s4.w));
        } else {
            r = make_float4(scale * acc.x, scale * acc.y, scale * acc.z, scale * acc.w);
        }
        *reinterpret_cast<float4*>(&C[i][q * 4]) = r;
    }
}

// ---------------------------------------------------------------------------
// K1: wavelet basis. One block per sample. lambda_max via 5 matrix squarings
// (L^64, parallel work) + 4 shfl matvec iterations; 64th root kills the error.
// ---------------------------------------------------------------------------
__global__ __launch_bounds__(256) void k_wavelet(const float* __restrict__ G,
                                                 float* __restrict__ Wo,
                                                 float* __restrict__ Wio)
{
    __shared__ float sG[NN][PW];    // G -> squaring ping -> W scratch
    __shared__ float sL[NN][PW];
    __shared__ float sT2[NN][PW];
    __shared__ float sT3[NN][PW];
    __shared__ float sM[NN][PW];    // squaring pong, final L^64
    __shared__ float sdeg[NN], sdinv[NN], srs[NN];
    __shared__ float slam64;

    const int b   = blockIdx.x;
    const int tid = threadIdx.x;
    const float* Gb = G + (size_t)b * NN * NN;

    for (int e = tid; e < NN * PW; e += 256) {
        const int i = e / PW, j = e % PW;
        sG[i][j] = (j < NN) ? Gb[i * NN + j] : 0.0f;
    }
    __syncthreads();

    if (tid < NN) {
        float4 s4 = make_float4(0.f, 0.f, 0.f, 0.f);
        #pragma unroll
        for (int q = 0; q < 11; ++q) {
            const float4 g4 = *reinterpret_cast<const float4*>(&sG[tid][q * 4]);
            s4.x += g4.x; s4.y += g4.y; s4.z += g4.z; s4.w += g4.w;
        }
        const float s = (s4.x + s4.y) + (s4.z + s4.w);
        sdeg[tid]  = s;
        sdinv[tid] = 1.0f / (sqrtf(s) + 1e-6f);
    }
    __syncthreads();

    for (int e = tid; e < NN * PW; e += 256) {
        const int i = e / PW, j = e % PW;
        if (j < NN) {
            const float a = 0.5f * (sG[i][j] + sG[j][i]);
            const float v = ((i == j) ? sdeg[i] : 0.0f) - a;
            sL[i][j] = sdinv[i] * sdinv[j] * v;
        } else {
            sL[i][j] = 0.0f;
        }
    }
    __syncthreads();

    lds_mm(sL, sL, sT2, 2.0f, nullptr, tid);   // T2 = 2 L^2
    __syncthreads();
    lds_mm(sL, sT2, sT3, 2.0f, sL, tid);       // T3 = 2 L T2 - L
    __syncthreads();

    // ---- lambda_max via repeated squaring: L^4, L^8, L^16, L^32, L^64 ----
    lds_mm(sT2, sT2, sM, 0.25f, nullptr, tid); // (2L^2)^2/4 = L^4
    __syncthreads();
    lds_mm(sM, sM, sG, 1.0f, nullptr, tid);    // L^8   (G no longer needed)
    __syncthreads();
    lds_mm(sG, sG, sM, 1.0f, nullptr, tid);    // L^16
    __syncthreads();
    lds_mm(sM, sM, sG, 1.0f, nullptr, tid);    // L^32
    __syncthreads();
    lds_mm(sG, sG, sM, 1.0f, nullptr, tid);    // L^64 -> sM
    __syncthreads();

    if (tid < 64) {
        float lr[NN];
        #pragma unroll
        for (int j = 0; j < NN; ++j) lr[j] = (tid < NN) ? sM[tid][j] : 0.0f;
        unsigned h = (unsigned)(tid + 1) * 2654435761u;
        h ^= h >> 13; h *= 0x85ebca6bu; h ^= h >> 16;
        float v = (tid < NN) ? (0.25f + (float)(h & 1023) * (1.0f / 1024.0f)) : 0.0f;
        // normalize v0
        float n2 = v * v;
        #pragma unroll
        for (int off = 32; off > 0; off >>= 1) n2 += __shfl_xor(n2, off, 64);
        v *= rsqrtf(n2);
        float lam64 = 1.0f;
        #pragma unroll
        for (int it = 0; it < 4; ++it) {
            float acc = 0.f;
            #pragma unroll
            for (int j = 0; j < NN; ++j) acc = fmaf(lr[j], __shfl(v, j, 64), acc);
            float m2 = acc * acc;
            #pragma unroll
            for (int off = 32; off > 0; off >>= 1) m2 += __shfl_xor(m2, off, 64);
            lam64 = sqrtf(m2);                 // ||M v||, with ||v|| = 1
            v = acc * (1.0f / lam64);
        }
        if (tid == 0) slam64 = lam64;
    }
    __syncthreads();

    const float x = 0.15f * exp2f(log2f(slam64) * (1.0f / 64.0f));  // S*lam/2
    float iv[4];
    {
        const float xh = 0.5f * x, xh2 = xh * xh;
        #pragma unroll
        for (int n = 0; n < 4; ++n) {
            float c = 1.0f;                  // 1/n!
            for (int q = 2; q <= n; ++q) c /= (float)q;
            float p = 1.0f;                  // xh^n
            for (int q = 0; q < n; ++q) p *= xh;
            float s = 0.f;
            for (int k = 0; k < 25; ++k) {
                s += c * p;
                p *= xh2;
                c /= (float)((k + 1) * (k + 1 + n));
            }
            iv[n] = s;
        }
    }
    const float ex = expf(x), emx = expf(-x);
    #pragma unroll
    for (int pass = 0; pass < 2; ++pass) {
        const float a1 = pass ? (-2.f * emx * iv[1]) : (2.f * ex * iv[1]);
        const float a2 = pass ? ( 2.f * emx * iv[2]) : (2.f * ex * iv[2]);
        const float a3 = pass ? (-2.f * emx * iv[3]) : (2.f * ex * iv[3]);
        for (int s = tid; s < NN * 11; s += 256) {
            const int i = s / 11, q = s % 11;
            const float4 l4  = *reinterpret_cast<const float4*>(&sL[i][q * 4]);
            const float4 t24 = *reinterpret_cast<const float4*>(&sT2[i][q * 4]);
            const float4 t34 = *reinterpret_cast<const float4*>(&sT3[i][q * 4]);
            float4 w;
            w.x = fmaf(a1, l4.x, fmaf(a2, t24.x, a3 * t34.x));
            w.y = fmaf(a1, l4.y, fmaf(a2, t24.y, a3 * t34.y));
            w.z = fmaf(a1, l4.z, fmaf(a2, t24.z, a3 * t34.z));
            w.w = fmaf(a1, l4.w, fmaf(a2, t24.w, a3 * t34.w));
            w.x = (w.x < 1e-4f) ? 0.f : w.x;  w.y = (w.y < 1e-4f) ? 0.f : w.y;
            w.z = (w.z < 1e-4f) ? 0.f : w.z;  w.w = (w.w < 1e-4f) ? 0.f : w.w;
            *reinterpret_cast<float4*>(&sG[i][q * 4]) = w;
        }
        __syncthreads();
        if (tid < NN) {
            float s = 0.f;
            #pragma unroll
            for (int q = 0; q < 11; ++q) {
                const float4 w4 = *reinterpret_cast<const float4*>(&sG[tid][q * 4]);
                s += fabsf(w4.x) + fabsf(w4.y) + fabsf(w4.z) + fabsf(w4.w);
            }
            srs[tid] = 1.0f / fmaxf(s, 1e-12f);
        }
        __syncthreads();
        float* dst = (pass ? Wio : Wo) + (size_t)b * NN * NN;
        for (int e = tid; e < NN * NN; e += 256) dst[e] = sG[e / NN][e % NN] * srs[e / NN];
        __syncthreads();
    }
}

// ---------------------------------------------------------------------------
// K2/K4: generic f32 GEMM  C[M,271] = act(A[M,271] @ Bm[271,271] + bias)
// 64x64 tile, 256 threads, 4x4 micro-tile, K-tile 16. M divisible by 64.
// ---------------------------------------------------------------------------
__global__ __launch_bounds__(256) void k_gemm271(const float* __restrict__ A,
                                                 const float* __restrict__ Bm,
                                                 const float* __restrict__ bias,
                                                 float* __restrict__ C,
                                                 const int relu)
{
    __shared__ float As[16][68];   // [k][m]
    __shared__ float Bs[16][68];   // [k][n]
    const int tid = threadIdx.x;
    const int tx = tid & 15, ty = tid >> 4;
    const long long row0 = (long long)blockIdx.x * 64;
    const int col0 = blockIdx.y * 64;
    float acc[4][4] = {};

    for (int kt = 0; kt < DD; kt += 16) {
        for (int l = tid; l < 64 * 16; l += 256) {
            int m = l >> 4, k = l & 15;
            int kk = kt + k;
            As[k][m] = (kk < DD) ? A[(row0 + m) * DD + kk] : 0.0f;
        }
        for (int l = tid; l < 16 * 64; l += 256) {
            int k = l >> 6, n = l & 63;
            int kk = kt + k, cn = col0 + n;
            Bs[k][n] = (kk < DD && cn < DD) ? Bm[(size_t)kk * DD + cn] : 0.0f;
        }
        __syncthreads();
        #pragma unroll
        for (int k = 0; k < 16; ++k) {
            const float4 a4 = *reinterpret_cast<const float4*>(&As[k][ty * 4]);
            const float4 b4 = *reinterpret_cast<const float4*>(&Bs[k][tx * 4]);
            const float av[4] = {a4.x, a4.y, a4.z, a4.w};
            const float bv[4] = {b4.x, b4.y, b4.z, b4.w};
            #pragma unroll
            for (int r = 0; r < 4; ++r)
                #pragma unroll
                for (int c = 0; c < 4; ++c)
                    acc[r][c] = fmaf(av[r], bv[c], acc[r][c]);
        }
        __syncthreads();
    }
    #pragma unroll
    for (int r = 0; r < 4; ++r) {
        const long long row = row0 + ty * 4 + r;
        #pragma unroll
        for (int c = 0; c < 4; ++c) {
            const int col = col0 + tx * 4 + c;
            if (col < DD) {
                float v = acc[r][c] + (bias ? bias[col] : 0.0f);
                if (relu) v = fmaxf(v, 0.0f);
                C[row * DD + col] = v;
            }
        }
    }
}

// ---------------------------------------------------------------------------
// K3: per-sample wavelet application, in-place on h:
//   h <- exp(lsv) * relu( W @ (gk .* (Wi @ h)) )
// ---------------------------------------------------------------------------
__global__ __launch_bounds__(256) void k_wavapply(const float* __restrict__ Wwav,
                                                  const float* __restrict__ Wiwav,
                                                  const float* __restrict__ gk,
                                                  const float* __restrict__ lsv,
                                                  float* __restrict__ h)
{
    constexpr int CW = 68;   // chunk width
    constexpr int PS = 60;   // padded stride
    __shared__ float sWi[NN][PW];
    __shared__ float sW[NN][PW];
    __shared__ float shT[CW][PS];
    __shared__ float stT[CW][PS];
    __shared__ float sgk[NN];

    const int b   = blockIdx.x;
    const int c0  = blockIdx.y * CW;
    const int tid = threadIdx.x;
    const float* Wb  = Wwav  + (size_t)b * NN * NN;
    const float* Wib = Wiwav + (size_t)b * NN * NN;

    for (int e = tid; e < NN * PW; e += 256) {
        int i = e / PW, j = e % PW;
        float wv = 0.f, wiv = 0.f;
        if (j < NN) { wv = Wb[i * NN + j]; wiv = Wib[i * NN + j]; }
        sW[i][j] = wv; sWi[i][j] = wiv;
    }
    if (tid < NN) sgk[tid] = gk[tid];
    for (int e = tid; e < NN * CW; e += 256) {
        int i = e / CW, c = e % CW;
        int cc = c0 + c;
        shT[c][i] = (cc < DD) ? h[((size_t)b * NN + i) * DD + cc] : 0.0f;
    }
    for (int e = tid; e < CW * 3; e += 256) {
        int c = e / 3, j = NN + (e % 3);
        shT[c][j] = 0.f; stT[c][j] = 0.f;
    }
    __syncthreads();

    for (int e = tid; e < NN * CW; e += 256) {
        int i = e / CW, c = e % CW;
        float acc = 0.f;
        #pragma unroll
        for (int q = 0; q < 11; ++q) {
            const float4 w4 = *reinterpret_cast<const float4*>(&sWi[i][q * 4]);
            const float4 h4 = *reinterpret_cast<const float4*>(&shT[c][q * 4]);
            acc = fmaf(w4.x, h4.x, acc); acc = fmaf(w4.y, h4.y, acc);
            acc = fmaf(w4.z, h4.z, acc); acc = fmaf(w4.w, h4.w, acc);
        }
        stT[c][i] = sgk[i] * acc;
    }
    __syncthreads();

    for (int e = tid; e < NN * CW; e += 256) {
        int i = e / CW, c = e % CW;
        int cc = c0 + c;
        if (cc < DD) {
            float acc = 0.f;
            #pragma unroll
            for (int q = 0; q < 11; ++q) {
                const float4 w4 = *reinterpret_cast<const float4*>(&sW[i][q * 4]);
                const float4 t4 = *reinterpret_cast<const float4*>(&stT[c][q * 4]);
                acc = fmaf(w4.x, t4.x, acc); acc = fmaf(w4.y, t4.y, acc);
                acc = fmaf(w4.z, t4.z, acc); acc = fmaf(w4.w, t4.w, acc);
            }
            acc = fmaxf(acc, 0.0f) * expf(lsv[i * DD + cc]);
            h[((size_t)b * NN + i) * DD + cc] = acc;
        }
    }
}

// ---------------------------------------------------------------------------
__global__ __launch_bounds__(256) void k_mean(const float* __restrict__ fr, float* __restrict__ seq)
{
    const int b = blockIdx.x;
    for (int d = threadIdx.x; d < DD; d += 256) {
        float s = 0.f;
        #pragma unroll
        for (int n = 0; n < NN; ++n) s += fr[((size_t)b * NN + n) * DD + d];
        seq[(size_t)b * DD + d] = s * (1.0f / 41.0f);
    }
}

__global__ __launch_bounds__(256) void k_stats(const float* __restrict__ seq, float* __restrict__ stats)
{
    __shared__ float s1[256], s2[256];
    const int d = blockIdx.x;
    float a = 0.f, q = 0.f;
    for (int b = threadIdx.x; b < BB; b += 256) {
        float v = seq[(size_t)b * DD + d];
        a += v; q = fmaf(v, v, q);
    }
    s1[threadIdx.x] = a; s2[threadIdx.x] = q;
    __syncthreads();
    for (int o = 128; o > 0; o >>= 1) {
        if (threadIdx.x < o) { s1[threadIdx.x] += s1[threadIdx.x + o]; s2[threadIdx.x] += s2[threadIdx.x + o]; }
        __syncthreads();
    }
    if (threadIdx.x == 0) {
        float m = s1[0] * (1.0f / BB);
        float v = s2[0] * (1.0f / BB) - m * m;
        stats[d]      = m;
        stats[DD + d] = 1.0f / sqrtf(v + 1e-5f);
    }
}

__global__ __launch_bounds__(256) void k_bn(const float* __restrict__ seq, const float* __restrict__ stats,
                                            const float* __restrict__ g, const float* __restrict__ bt,
                                            float* __restrict__ out)
{
    const long long idx = (long long)blockIdx.x * 256 + threadIdx.x;
    if (idx < (long long)BB * DD) {
        const int d = (int)(idx % DD);
        out[idx] = (seq[idx] - stats[d]) * stats[DD + d] * g[d] + bt[d];
    }
}

// ---------------------------------------------------------------------------
extern "C" void kernel_launch(void* const* d_in, const int* in_sizes, int n_in,
                              void* d_out, int out_size, void* d_ws, size_t ws_size,
                              hipStream_t stream)
{
    const float* G   = (const float*)d_in[0];
    const float* X   = (const float*)d_in[1];
    const float* gk  = (const float*)d_in[2];
    const float* gW  = (const float*)d_in[3];
    const float* lsv = (const float*)d_in[4];
    const float* W1  = (const float*)d_in[5];
    const float* b1  = (const float*)d_in[6];
    const float* W2  = (const float*)d_in[7];
    const float* b2  = (const float*)d_in[8];
    const float* gam = (const float*)d_in[9];
    const float* bet = (const float*)d_in[10];

    float* ws = (float*)d_ws;
    size_t off = 0;
    float* Wwav  = ws + off; off += (size_t)BB * NN * NN;
    float* Wiwav = ws + off; off += (size_t)BB * NN * NN;
    float* bufA  = ws + off; off += (size_t)BB * NN * DD;
    float* bufB  = ws + off; off += (size_t)BB * NN * DD;
    float* seq   = ws + off; off += (size_t)BB * DD;
    float* stats = ws + off; off += 2 * DD;

    k_wavelet<<<BB, 256, 0, stream>>>(G, Wwav, Wiwav);
    k_gemm271<<<dim3((unsigned)(MROWS / 64), 5), 256, 0, stream>>>(X, gW, nullptr, bufA, 0);
    k_wavapply<<<dim3(BB, 4), 256, 0, stream>>>(Wwav, Wiwav, gk, lsv, bufA);
    k_gemm271<<<dim3((unsigned)(MROWS / 64), 5), 256, 0, stream>>>(bufA, W1, b1, bufB, 1);
    k_gemm271<<<dim3((unsigned)(MROWS / 64), 5), 256, 0, stream>>>(bufB, W2, b2, bufA, 0);
    k_mean<<<BB, 256, 0, stream>>>(bufA, seq);
    k_stats<<<DD, 256, 0, stream>>>(seq, stats);
    k_bn<<<(unsigned)(((long long)BB * DD + 255) / 256), 256, 0, stream>>>(seq, stats, gam, bet, (float*)d_out);
}

// Round 3
// 1285.134 us; speedup vs baseline: 2.3935x; 1.6693x over previous
//
#include <hip/hip_runtime.h>
#include <math.h>

namespace {
constexpr int BB = 4096;   // batch
constexpr int NN = 41;     // nodes
constexpr int DD = 271;    // features
constexpr int DP = 288;    // padded feature dim (multiple of 32)
constexpr int PW = 44;     // padded row stride for 41-wide LDS matrices
constexpr long long MROWS = (long long)BB * NN;   // 167936
}

typedef __attribute__((ext_vector_type(8))) unsigned short ushort8;
typedef __attribute__((ext_vector_type(8))) short          short8;
typedef __attribute__((ext_vector_type(4))) float          f32x4;

__device__ __forceinline__ unsigned short f2bf(float f) {
    unsigned u = __float_as_uint(f);
    unsigned r = (u + 0x7FFFu + ((u >> 16) & 1u)) >> 16;
    return (unsigned short)r;
}
__device__ __forceinline__ float bf2f(unsigned short h) {
    return __uint_as_float(((unsigned)h) << 16);
}

// ---------------------------------------------------------------------------
// LDS matmul helper: C = scale * A@B - (sub ? sub : 0), 41x41, stride-44 rows.
// ---------------------------------------------------------------------------
__device__ __forceinline__ void lds_mm(const float (*__restrict__ A)[PW],
                                       const float (*__restrict__ B)[PW],
                                       float (*__restrict__ C)[PW],
                                       const float scale,
                                       const float (*__restrict__ sub)[PW],
                                       const int tid)
{
    for (int s = tid; s < NN * 11; s += 256) {
        const int i = s / 11, q = s % 11;
        float4 acc = make_float4(0.f, 0.f, 0.f, 0.f);
        #pragma unroll
        for (int k = 0; k < NN; ++k) {
            const float a = A[i][k];
            const float4 b4 = *reinterpret_cast<const float4*>(&B[k][q * 4]);
            acc.x = fmaf(a, b4.x, acc.x); acc.y = fmaf(a, b4.y, acc.y);
            acc.z = fmaf(a, b4.z, acc.z); acc.w = fmaf(a, b4.w, acc.w);
        }
        float4 r;
        if (sub) {
            const float4 s4 = *reinterpret_cast<const float4*>(&sub[i][q * 4]);
            r = make_float4(fmaf(scale, acc.x, -s4.x), fmaf(scale, acc.y, -s4.y),
                            fmaf(scale, acc.z, -s4.z), fmaf(scale, acc.w, -s4.w));
        } else {
            r = make_float4(scale * acc.x, scale * acc.y, scale * acc.z, scale * acc.w);
        }
        *reinterpret_cast<float4*>(&C[i][q * 4]) = r;
    }
}

// ---------------------------------------------------------------------------
// K1: wavelet basis (unchanged from round 1).
// ---------------------------------------------------------------------------
__global__ __launch_bounds__(256) void k_wavelet(const float* __restrict__ G,
                                                 float* __restrict__ Wo,
                                                 float* __restrict__ Wio)
{
    __shared__ float sG[NN][PW];
    __shared__ float sL[NN][PW];
    __shared__ float sT2[NN][PW];
    __shared__ float sT3[NN][PW];
    __shared__ float sM[NN][PW];
    __shared__ float sdeg[NN], sdinv[NN], srs[NN];
    __shared__ float slam64;

    const int b   = blockIdx.x;
    const int tid = threadIdx.x;
    const float* Gb = G + (size_t)b * NN * NN;

    for (int e = tid; e < NN * PW; e += 256) {
        const int i = e / PW, j = e % PW;
        sG[i][j] = (j < NN) ? Gb[i * NN + j] : 0.0f;
    }
    __syncthreads();

    if (tid < NN) {
        float4 s4 = make_float4(0.f, 0.f, 0.f, 0.f);
        #pragma unroll
        for (int q = 0; q < 11; ++q) {
            const float4 g4 = *reinterpret_cast<const float4*>(&sG[tid][q * 4]);
            s4.x += g4.x; s4.y += g4.y; s4.z += g4.z; s4.w += g4.w;
        }
        const float s = (s4.x + s4.y) + (s4.z + s4.w);
        sdeg[tid]  = s;
        sdinv[tid] = 1.0f / (sqrtf(s) + 1e-6f);
    }
    __syncthreads();

    for (int e = tid; e < NN * PW; e += 256) {
        const int i = e / PW, j = e % PW;
        if (j < NN) {
            const float a = 0.5f * (sG[i][j] + sG[j][i]);
            const float v = ((i == j) ? sdeg[i] : 0.0f) - a;
            sL[i][j] = sdinv[i] * sdinv[j] * v;
        } else {
            sL[i][j] = 0.0f;
        }
    }
    __syncthreads();

    lds_mm(sL, sL, sT2, 2.0f, nullptr, tid);
    __syncthreads();
    lds_mm(sL, sT2, sT3, 2.0f, sL, tid);
    __syncthreads();

    lds_mm(sT2, sT2, sM, 0.25f, nullptr, tid); // L^4
    __syncthreads();
    lds_mm(sM, sM, sG, 1.0f, nullptr, tid);    // L^8
    __syncthreads();
    lds_mm(sG, sG, sM, 1.0f, nullptr, tid);    // L^16
    __syncthreads();
    lds_mm(sM, sM, sG, 1.0f, nullptr, tid);    // L^32
    __syncthreads();
    lds_mm(sG, sG, sM, 1.0f, nullptr, tid);    // L^64
    __syncthreads();

    if (tid < 64) {
        float lr[NN];
        #pragma unroll
        for (int j = 0; j < NN; ++j) lr[j] = (tid < NN) ? sM[tid][j] : 0.0f;
        unsigned h = (unsigned)(tid + 1) * 2654435761u;
        h ^= h >> 13; h *= 0x85ebca6bu; h ^= h >> 16;
        float v = (tid < NN) ? (0.25f + (float)(h & 1023) * (1.0f / 1024.0f)) : 0.0f;
        float n2 = v * v;
        #pragma unroll
        for (int off = 32; off > 0; off >>= 1) n2 += __shfl_xor(n2, off, 64);
        v *= rsqrtf(n2);
        float lam64 = 1.0f;
        #pragma unroll
        for (int it = 0; it < 4; ++it) {
            float acc = 0.f;
            #pragma unroll
            for (int j = 0; j < NN; ++j) acc = fmaf(lr[j], __shfl(v, j, 64), acc);
            float m2 = acc * acc;
            #pragma unroll
            for (int off = 32; off > 0; off >>= 1) m2 += __shfl_xor(m2, off, 64);
            lam64 = sqrtf(m2);
            v = acc * (1.0f / lam64);
        }
        if (tid == 0) slam64 = lam64;
    }
    __syncthreads();

    const float x = 0.15f * exp2f(log2f(slam64) * (1.0f / 64.0f));
    float iv[4];
    {
        const float xh = 0.5f * x, xh2 = xh * xh;
        #pragma unroll
        for (int n = 0; n < 4; ++n) {
            float c = 1.0f;
            for (int q = 2; q <= n; ++q) c /= (float)q;
            float p = 1.0f;
            for (int q = 0; q < n; ++q) p *= xh;
            float s = 0.f;
            for (int k = 0; k < 25; ++k) {
                s += c * p;
                p *= xh2;
                c /= (float)((k + 1) * (k + 1 + n));
            }
            iv[n] = s;
        }
    }
    const float ex = expf(x), emx = expf(-x);
    #pragma unroll
    for (int pass = 0; pass < 2; ++pass) {
        const float a1 = pass ? (-2.f * emx * iv[1]) : (2.f * ex * iv[1]);
        const float a2 = pass ? ( 2.f * emx * iv[2]) : (2.f * ex * iv[2]);
        const float a3 = pass ? (-2.f * emx * iv[3]) : (2.f * ex * iv[3]);
        for (int s = tid; s < NN * 11; s += 256) {
            const int i = s / 11, q = s % 11;
            const float4 l4  = *reinterpret_cast<const float4*>(&sL[i][q * 4]);
            const float4 t24 = *reinterpret_cast<const float4*>(&sT2[i][q * 4]);
            const float4 t34 = *reinterpret_cast<const float4*>(&sT3[i][q * 4]);
            float4 w;
            w.x = fmaf(a1, l4.x, fmaf(a2, t24.x, a3 * t34.x));
            w.y = fmaf(a1, l4.y, fmaf(a2, t24.y, a3 * t34.y));
            w.z = fmaf(a1, l4.z, fmaf(a2, t24.z, a3 * t34.z));
            w.w = fmaf(a1, l4.w, fmaf(a2, t24.w, a3 * t34.w));
            w.x = (w.x < 1e-4f) ? 0.f : w.x;  w.y = (w.y < 1e-4f) ? 0.f : w.y;
            w.z = (w.z < 1e-4f) ? 0.f : w.z;  w.w = (w.w < 1e-4f) ? 0.f : w.w;
            *reinterpret_cast<float4*>(&sG[i][q * 4]) = w;
        }
        __syncthreads();
        if (tid < NN) {
            float s = 0.f;
            #pragma unroll
            for (int q = 0; q < 11; ++q) {
                const float4 w4 = *reinterpret_cast<const float4*>(&sG[tid][q * 4]);
                s += fabsf(w4.x) + fabsf(w4.y) + fabsf(w4.z) + fabsf(w4.w);
            }
            srs[tid] = 1.0f / fmaxf(s, 1e-12f);
        }
        __syncthreads();
        float* dst = (pass ? Wio : Wo) + (size_t)b * NN * NN;
        for (int e = tid; e < NN * NN; e += 256) dst[e] = sG[e / NN][e % NN] * srs[e / NN];
        __syncthreads();
    }
}

// ---------------------------------------------------------------------------
// Prep: split weights into hi/lo bf16, transposed fragment-friendly [n][k],
// padded to 288x288, three weights back to back.
// ---------------------------------------------------------------------------
__global__ __launch_bounds__(256) void k_splitB(const float* __restrict__ gW,
                                                const float* __restrict__ W1,
                                                const float* __restrict__ W2,
                                                unsigned short* __restrict__ Bth,
                                                unsigned short* __restrict__ Btl)
{
    const int t = blockIdx.x * 256 + threadIdx.x;
    if (t >= 3 * DP * DP) return;
    const int w = t / (DP * DP);
    const int r = t % (DP * DP);
    const int n = r / DP, k = r % DP;
    const float* src = (w == 0) ? gW : ((w == 1) ? W1 : W2);
    const float v = (n < DD && k < DD) ? src[k * DD + n] : 0.0f;
    const unsigned short h = f2bf(v);
    Bth[t] = h;
    Btl[t] = f2bf(v - bf2f(h));
}

// ---------------------------------------------------------------------------
// Prep: split X [M][271] f32 -> hi/lo bf16 [M][288], zero-padded.
// ---------------------------------------------------------------------------
__global__ __launch_bounds__(256) void k_splitX(const float* __restrict__ X,
                                                unsigned short* __restrict__ Xhi,
                                                unsigned short* __restrict__ Xlo)
{
    const long long t = (long long)blockIdx.x * 256 + threadIdx.x;
    if (t >= MROWS * (DP / 8)) return;
    const long long m = t / (DP / 8);
    const int k0 = (int)(t % (DP / 8)) * 8;
    ushort8 h, l;
    #pragma unroll
    for (int j = 0; j < 8; ++j) {
        const int k = k0 + j;
        const float v = (k < DD) ? X[m * DD + k] : 0.0f;
        const unsigned short hh = f2bf(v);
        h[j] = hh;
        l[j] = f2bf(v - bf2f(hh));
    }
    *reinterpret_cast<ushort8*>(&Xhi[m * DP + k0]) = h;
    *reinterpret_cast<ushort8*>(&Xlo[m * DP + k0]) = l;
}

// ---------------------------------------------------------------------------
// MFMA GEMM: C[M,288] = act(A[M,288] @ B[288,288] + bias)
// A given as split (hi/lo) or single bf16; B always split, in [n][k] layout.
// BM=256, BN=96, BK=32; 4 waves, wave tile 64x96, 16x16x32 bf16 MFMA.
// LDS rows: 128B = 8 x 16B chunks (4 hi + 4 lo), XOR-swizzled by row&7.
// OMODE: 0 = f32 out, 1 = split bf16 out, 2 = single bf16 out.
// ---------------------------------------------------------------------------
template<bool SPLITA, int OMODE>
__global__ __launch_bounds__(256) void k_gemm_mfma(
    const unsigned short* __restrict__ Ahi, const unsigned short* __restrict__ Alo,
    const unsigned short* __restrict__ Bth, const unsigned short* __restrict__ Btl,
    const float* __restrict__ bias, const int relu,
    float* __restrict__ outF, unsigned short* __restrict__ outHi,
    unsigned short* __restrict__ outLo)
{
    __shared__ __align__(16) unsigned short A_l[256 * 64];
    __shared__ __align__(16) unsigned short B_l[96 * 64];
    const int tid  = threadIdx.x;
    const int lane = tid & 63, w = tid >> 6;
    const long long row0 = (long long)blockIdx.x * 256;
    const int n0 = blockIdx.y * 96;

    f32x4 acc[4][6];
    #pragma unroll
    for (int mf = 0; mf < 4; ++mf)
        #pragma unroll
        for (int nf = 0; nf < 6; ++nf)
            acc[mf][nf] = (f32x4){0.f, 0.f, 0.f, 0.f};

    for (int kt = 0; kt < DP; kt += 32) {
        // stage A tile (256 rows x 32 k)
        #pragma unroll
        for (int i = 0; i < 4; ++i) {
            const int q = tid + i * 256;
            const int m = q >> 2, c = q & 3;
            const long long g = (row0 + m) * DP + kt + c * 8;
            const ushort8 hv = *reinterpret_cast<const ushort8*>(Ahi + g);
            *reinterpret_cast<ushort8*>(&A_l[m * 64 + ((c ^ (m & 7)) * 8)]) = hv;
            if (SPLITA) {
                const ushort8 lv = *reinterpret_cast<const ushort8*>(Alo + g);
                *reinterpret_cast<ushort8*>(&A_l[m * 64 + (((c + 4) ^ (m & 7)) * 8)]) = lv;
            }
        }
        // stage B tile (96 rows x 32 k, hi + lo)
        #pragma unroll
        for (int i = 0; i < 2; ++i) {
            const int q = tid + i * 256;
            if (q < 96 * 4) {
                const int n = q >> 2, c = q & 3;
                const long long g = (long long)(n0 + n) * DP + kt + c * 8;
                const ushort8 hv = *reinterpret_cast<const ushort8*>(Bth + g);
                const ushort8 lv = *reinterpret_cast<const ushort8*>(Btl + g);
                *reinterpret_cast<ushort8*>(&B_l[n * 64 + ((c ^ (n & 7)) * 8)]) = hv;
                *reinterpret_cast<ushort8*>(&B_l[n * 64 + (((c + 4) ^ (n & 7)) * 8)]) = lv;
            }
        }
        __syncthreads();

        const int cb = lane >> 4;
        short8 ah[4], al[4];
        #pragma unroll
        for (int mf = 0; mf < 4; ++mf) {
            const int m = w * 64 + mf * 16 + (lane & 15);
            ah[mf] = *reinterpret_cast<const short8*>(&A_l[m * 64 + ((cb ^ (m & 7)) * 8)]);
            if (SPLITA)
                al[mf] = *reinterpret_cast<const short8*>(&A_l[m * 64 + (((cb + 4) ^ (m & 7)) * 8)]);
        }
        #pragma unroll
        for (int nf = 0; nf < 6; ++nf) {
            const int n = nf * 16 + (lane & 15);
            const short8 bh = *reinterpret_cast<const short8*>(&B_l[n * 64 + ((cb ^ (n & 7)) * 8)]);
            const short8 bl = *reinterpret_cast<const short8*>(&B_l[n * 64 + (((cb + 4) ^ (n & 7)) * 8)]);
            #pragma unroll
            for (int mf = 0; mf < 4; ++mf) {
                acc[mf][nf] = __builtin_amdgcn_mfma_f32_16x16x32_bf16(ah[mf], bh, acc[mf][nf], 0, 0, 0);
                if (SPLITA)
                    acc[mf][nf] = __builtin_amdgcn_mfma_f32_16x16x32_bf16(al[mf], bh, acc[mf][nf], 0, 0, 0);
                acc[mf][nf] = __builtin_amdgcn_mfma_f32_16x16x32_bf16(ah[mf], bl, acc[mf][nf], 0, 0, 0);
            }
        }
        __syncthreads();
    }

    // epilogue: C row = row0 + w*64 + mf*16 + (lane>>4)*4 + r, col = n0 + nf*16 + (lane&15)
    #pragma unroll
    for (int mf = 0; mf < 4; ++mf) {
        const long long rbase = row0 + w * 64 + mf * 16 + ((lane >> 4) * 4);
        #pragma unroll
        for (int nf = 0; nf < 6; ++nf) {
            const int col = n0 + nf * 16 + (lane & 15);
            const float bv = (bias && col < DD) ? bias[col] : 0.0f;
            #pragma unroll
            for (int r = 0; r < 4; ++r) {
                float v = acc[mf][nf][r] + bv;
                if (relu) v = fmaxf(v, 0.f);
                const long long idx = (rbase + r) * DP + col;
                if (OMODE == 0) {
                    outF[idx] = v;
                } else if (OMODE == 2) {
                    outHi[idx] = f2bf(v);
                } else {
                    const unsigned short h = f2bf(v);
                    outHi[idx] = h;
                    outLo[idx] = f2bf(v - bf2f(h));
                }
            }
        }
    }
}

// ---------------------------------------------------------------------------
// K3: per-sample wavelet application: reads f32 h [M][288]-strided,
// writes split bf16: out <- exp(lsv) * relu( W @ (gk .* (Wi @ h)) )
// ---------------------------------------------------------------------------
__global__ __launch_bounds__(256) void k_wavapply(const float* __restrict__ Wwav,
                                                  const float* __restrict__ Wiwav,
                                                  const float* __restrict__ gk,
                                                  const float* __restrict__ lsv,
                                                  const float* __restrict__ h,
                                                  unsigned short* __restrict__ Ohi,
                                                  unsigned short* __restrict__ Olo)
{
    constexpr int CW = 68;
    constexpr int PS = 60;
    __shared__ float sWi[NN][PW];
    __shared__ float sW[NN][PW];
    __shared__ float shT[CW][PS];
    __shared__ float stT[CW][PS];
    __shared__ float sgk[NN];

    const int b   = blockIdx.x;
    const int c0  = blockIdx.y * CW;
    const int tid = threadIdx.x;
    const float* Wb  = Wwav  + (size_t)b * NN * NN;
    const float* Wib = Wiwav + (size_t)b * NN * NN;

    for (int e = tid; e < NN * PW; e += 256) {
        int i = e / PW, j = e % PW;
        float wv = 0.f, wiv = 0.f;
        if (j < NN) { wv = Wb[i * NN + j]; wiv = Wib[i * NN + j]; }
        sW[i][j] = wv; sWi[i][j] = wiv;
    }
    if (tid < NN) sgk[tid] = gk[tid];
    for (int e = tid; e < NN * CW; e += 256) {
        int i = e / CW, c = e % CW;
        int cc = c0 + c;
        shT[c][i] = (cc < DD) ? h[((size_t)b * NN + i) * DP + cc] : 0.0f;
    }
    for (int e = tid; e < CW * 3; e += 256) {
        int c = e / 3, j = NN + (e % 3);
        shT[c][j] = 0.f; stT[c][j] = 0.f;
    }
    __syncthreads();

    for (int e = tid; e < NN * CW; e += 256) {
        int i = e / CW, c = e % CW;
        float acc = 0.f;
        #pragma unroll
        for (int q = 0; q < 11; ++q) {
            const float4 w4 = *reinterpret_cast<const float4*>(&sWi[i][q * 4]);
            const float4 h4 = *reinterpret_cast<const float4*>(&shT[c][q * 4]);
            acc = fmaf(w4.x, h4.x, acc); acc = fmaf(w4.y, h4.y, acc);
            acc = fmaf(w4.z, h4.z, acc); acc = fmaf(w4.w, h4.w, acc);
        }
        stT[c][i] = sgk[i] * acc;
    }
    __syncthreads();

    for (int e = tid; e < NN * CW; e += 256) {
        int i = e / CW, c = e % CW;
        int cc = c0 + c;
        if (cc < DD) {
            float acc = 0.f;
            #pragma unroll
            for (int q = 0; q < 11; ++q) {
                const float4 w4 = *reinterpret_cast<const float4*>(&sW[i][q * 4]);
                const float4 t4 = *reinterpret_cast<const float4*>(&stT[c][q * 4]);
                acc = fmaf(w4.x, t4.x, acc); acc = fmaf(w4.y, t4.y, acc);
                acc = fmaf(w4.z, t4.z, acc); acc = fmaf(w4.w, t4.w, acc);
            }
            acc = fmaxf(acc, 0.0f) * expf(lsv[i * DD + cc]);
            const long long idx = ((size_t)b * NN + i) * DP + cc;
            const unsigned short hh = f2bf(acc);
            Ohi[idx] = hh;
            Olo[idx] = f2bf(acc - bf2f(hh));
        }
    }
}

// ---------------------------------------------------------------------------
__global__ __launch_bounds__(256) void k_mean(const float* __restrict__ fr, float* __restrict__ seq)
{
    const int b = blockIdx.x;
    for (int d = threadIdx.x; d < DD; d += 256) {
        float s = 0.f;
        #pragma unroll
        for (int n = 0; n < NN; ++n) s += fr[((size_t)b * NN + n) * DP + d];
        seq[(size_t)b * DD + d] = s * (1.0f / 41.0f);
    }
}

__global__ __launch_bounds__(256) void k_stats(const float* __restrict__ seq, float* __restrict__ stats)
{
    __shared__ float s1[256], s2[256];
    const int d = blockIdx.x;
    float a = 0.f, q = 0.f;
    for (int b = threadIdx.x; b < BB; b += 256) {
        float v = seq[(size_t)b * DD + d];
        a += v; q = fmaf(v, v, q);
    }
    s1[threadIdx.x] = a; s2[threadIdx.x] = q;
    __syncthreads();
    for (int o = 128; o > 0; o >>= 1) {
        if (threadIdx.x < o) { s1[threadIdx.x] += s1[threadIdx.x + o]; s2[threadIdx.x] += s2[threadIdx.x + o]; }
        __syncthreads();
    }
    if (threadIdx.x == 0) {
        float m = s1[0] * (1.0f / BB);
        float v = s2[0] * (1.0f / BB) - m * m;
        stats[d]      = m;
        stats[DD + d] = 1.0f / sqrtf(v + 1e-5f);
    }
}

__global__ __launch_bounds__(256) void k_bn(const float* __restrict__ seq, const float* __restrict__ stats,
                                            const float* __restrict__ g, const float* __restrict__ bt,
                                            float* __restrict__ out)
{
    const long long idx = (long long)blockIdx.x * 256 + threadIdx.x;
    if (idx < (long long)BB * DD) {
        const int d = (int)(idx % DD);
        out[idx] = (seq[idx] - stats[d]) * stats[DD + d] * g[d] + bt[d];
    }
}

// ---------------------------------------------------------------------------
extern "C" void kernel_launch(void* const* d_in, const int* in_sizes, int n_in,
                              void* d_out, int out_size, void* d_ws, size_t ws_size,
                              hipStream_t stream)
{
    const float* G   = (const float*)d_in[0];
    const float* X   = (const float*)d_in[1];
    const float* gk  = (const float*)d_in[2];
    const float* gW  = (const float*)d_in[3];
    const float* lsv = (const float*)d_in[4];
    const float* W1  = (const float*)d_in[5];
    const float* b1  = (const float*)d_in[6];
    const float* W2  = (const float*)d_in[7];
    const float* b2  = (const float*)d_in[8];
    const float* gam = (const float*)d_in[9];
    const float* bet = (const float*)d_in[10];

    char* p = (char*)d_ws;
    auto alloc = [&](size_t bytes) { void* r = (void*)p; p += (bytes + 255) & ~(size_t)255; return r; };
    const size_t MD  = (size_t)MROWS * DP;              // padded activation elems
    float*          Wwav  = (float*)alloc((size_t)BB * NN * NN * 4);
    float*          Wiwav = (float*)alloc((size_t)BB * NN * NN * 4);
    unsigned short* Shi   = (unsigned short*)alloc(MD * 2);   // X split / wavapply out
    unsigned short* Slo   = (unsigned short*)alloc(MD * 2);
    float*          bufA  = (float*)alloc(MD * 4);            // gemm1 out f32, reused gemm3 out
    unsigned short* P2    = (unsigned short*)alloc(MD * 2);   // gemm2 out (single bf16)
    unsigned short* Bth   = (unsigned short*)alloc((size_t)3 * DP * DP * 2);
    unsigned short* Btl   = (unsigned short*)alloc((size_t)3 * DP * DP * 2);
    float*          seq   = (float*)alloc((size_t)BB * DD * 4);
    float*          stats = (float*)alloc(2 * DD * 4);

    const int WB = DP * DP;   // per-weight Bt stride

    k_wavelet<<<BB, 256, 0, stream>>>(G, Wwav, Wiwav);
    k_splitB<<<(3 * DP * DP + 255) / 256, 256, 0, stream>>>(gW, W1, W2, Bth, Btl);
    k_splitX<<<(unsigned)((MROWS * (DP / 8) + 255) / 256), 256, 0, stream>>>(X, Shi, Slo);

    dim3 ggrid((unsigned)(MROWS / 256), 3);
    // GEMM1: h = X @ gW          (split A, f32 out)
    k_gemm_mfma<true, 0><<<ggrid, 256, 0, stream>>>(Shi, Slo, Bth, Btl, nullptr, 0,
                                                    bufA, nullptr, nullptr);
    // wavelet apply: bufA -> split bf16 into Shi/Slo
    k_wavapply<<<dim3(BB, 4), 256, 0, stream>>>(Wwav, Wiwav, gk, lsv, bufA, Shi, Slo);
    // GEMM2: relu(. @ W1 + b1)   (split A, single-bf16 out)
    k_gemm_mfma<true, 2><<<ggrid, 256, 0, stream>>>(Shi, Slo, Bth + WB, Btl + WB, b1, 1,
                                                    nullptr, P2, nullptr);
    // GEMM3: . @ W2 + b2         (single A, f32 out)
    k_gemm_mfma<false, 0><<<ggrid, 256, 0, stream>>>(P2, nullptr, Bth + 2 * WB, Btl + 2 * WB, b2, 0,
                                                     bufA, nullptr, nullptr);
    k_mean<<<BB, 256, 0, stream>>>(bufA, seq);
    k_stats<<<DD, 256, 0, stream>>>(seq, stats);
    k_bn<<<(unsigned)(((long long)BB * DD + 255) / 256), 256, 0, stream>>>(seq, stats, gam, bet, (float*)d_out);
}

// Round 4
// 1144.083 us; speedup vs baseline: 2.6886x; 1.1233x over previous
//
#include <hip/hip_runtime.h>
#include <math.h>

namespace {
constexpr int BB = 4096;   // batch
constexpr int NN = 41;     // nodes
constexpr int DD = 271;    // features
constexpr int DP = 288;    // padded feature dim (multiple of 32)
constexpr int PW = 44;     // padded row stride for 41-wide LDS matrices
constexpr long long MROWS = (long long)BB * NN;   // 167936
}

typedef __attribute__((ext_vector_type(8))) unsigned short ushort8;
typedef __attribute__((ext_vector_type(8))) short          short8;
typedef __attribute__((ext_vector_type(4))) float          f32x4;

__device__ __forceinline__ unsigned short f2bf(float f) {
    unsigned u = __float_as_uint(f);
    unsigned r = (u + 0x7FFFu + ((u >> 16) & 1u)) >> 16;
    return (unsigned short)r;
}
__device__ __forceinline__ float bf2f(unsigned short h) {
    return __uint_as_float(((unsigned)h) << 16);
}

// ---------------------------------------------------------------------------
// LDS matmul helper: C = scale * A@B - (sub ? sub : 0), 41x41, stride-44 rows.
// ---------------------------------------------------------------------------
__device__ __forceinline__ void lds_mm(const float (*__restrict__ A)[PW],
                                       const float (*__restrict__ B)[PW],
                                       float (*__restrict__ C)[PW],
                                       const float scale,
                                       const float (*__restrict__ sub)[PW],
                                       const int tid)
{
    for (int s = tid; s < NN * 11; s += 256) {
        const int i = s / 11, q = s % 11;
        float4 acc = make_float4(0.f, 0.f, 0.f, 0.f);
        #pragma unroll
        for (int k = 0; k < NN; ++k) {
            const float a = A[i][k];
            const float4 b4 = *reinterpret_cast<const float4*>(&B[k][q * 4]);
            acc.x = fmaf(a, b4.x, acc.x); acc.y = fmaf(a, b4.y, acc.y);
            acc.z = fmaf(a, b4.z, acc.z); acc.w = fmaf(a, b4.w, acc.w);
        }
        float4 r;
        if (sub) {
            const float4 s4 = *reinterpret_cast<const float4*>(&sub[i][q * 4]);
            r = make_float4(fmaf(scale, acc.x, -s4.x), fmaf(scale, acc.y, -s4.y),
                            fmaf(scale, acc.z, -s4.z), fmaf(scale, acc.w, -s4.w));
        } else {
            r = make_float4(scale * acc.x, scale * acc.y, scale * acc.z, scale * acc.w);
        }
        *reinterpret_cast<float4*>(&C[i][q * 4]) = r;
    }
}

// ---------------------------------------------------------------------------
// K1: wavelet basis. Pass 0 now writes W TRANSPOSED (WoT[j][i] = W[i][j]) so
// k_wavapply can scalar-load W columns contiguously. Pass 1 (Wi) normal.
// ---------------------------------------------------------------------------
__global__ __launch_bounds__(256) void k_wavelet(const float* __restrict__ G,
                                                 float* __restrict__ WoT,
                                                 float* __restrict__ Wio)
{
    __shared__ float sG[NN][PW];
    __shared__ float sL[NN][PW];
    __shared__ float sT2[NN][PW];
    __shared__ float sT3[NN][PW];
    __shared__ float sM[NN][PW];
    __shared__ float sdeg[NN], sdinv[NN], srs[NN];
    __shared__ float slam64;

    const int b   = blockIdx.x;
    const int tid = threadIdx.x;
    const float* Gb = G + (size_t)b * NN * NN;

    for (int e = tid; e < NN * PW; e += 256) {
        const int i = e / PW, j = e % PW;
        sG[i][j] = (j < NN) ? Gb[i * NN + j] : 0.0f;
    }
    __syncthreads();

    if (tid < NN) {
        float4 s4 = make_float4(0.f, 0.f, 0.f, 0.f);
        #pragma unroll
        for (int q = 0; q < 11; ++q) {
            const float4 g4 = *reinterpret_cast<const float4*>(&sG[tid][q * 4]);
            s4.x += g4.x; s4.y += g4.y; s4.z += g4.z; s4.w += g4.w;
        }
        const float s = (s4.x + s4.y) + (s4.z + s4.w);
        sdeg[tid]  = s;
        sdinv[tid] = 1.0f / (sqrtf(s) + 1e-6f);
    }
    __syncthreads();

    for (int e = tid; e < NN * PW; e += 256) {
        const int i = e / PW, j = e % PW;
        if (j < NN) {
            const float a = 0.5f * (sG[i][j] + sG[j][i]);
            const float v = ((i == j) ? sdeg[i] : 0.0f) - a;
            sL[i][j] = sdinv[i] * sdinv[j] * v;
        } else {
            sL[i][j] = 0.0f;
        }
    }
    __syncthreads();

    lds_mm(sL, sL, sT2, 2.0f, nullptr, tid);
    __syncthreads();
    lds_mm(sL, sT2, sT3, 2.0f, sL, tid);
    __syncthreads();

    lds_mm(sT2, sT2, sM, 0.25f, nullptr, tid); // L^4
    __syncthreads();
    lds_mm(sM, sM, sG, 1.0f, nullptr, tid);    // L^8
    __syncthreads();
    lds_mm(sG, sG, sM, 1.0f, nullptr, tid);    // L^16
    __syncthreads();
    lds_mm(sM, sM, sG, 1.0f, nullptr, tid);    // L^32
    __syncthreads();
    lds_mm(sG, sG, sM, 1.0f, nullptr, tid);    // L^64
    __syncthreads();

    if (tid < 64) {
        float lr[NN];
        #pragma unroll
        for (int j = 0; j < NN; ++j) lr[j] = (tid < NN) ? sM[tid][j] : 0.0f;
        unsigned h = (unsigned)(tid + 1) * 2654435761u;
        h ^= h >> 13; h *= 0x85ebca6bu; h ^= h >> 16;
        float v = (tid < NN) ? (0.25f + (float)(h & 1023) * (1.0f / 1024.0f)) : 0.0f;
        float n2 = v * v;
        #pragma unroll
        for (int off = 32; off > 0; off >>= 1) n2 += __shfl_xor(n2, off, 64);
        v *= rsqrtf(n2);
        float lam64 = 1.0f;
        #pragma unroll
        for (int it = 0; it < 4; ++it) {
            float acc = 0.f;
            #pragma unroll
            for (int j = 0; j < NN; ++j) acc = fmaf(lr[j], __shfl(v, j, 64), acc);
            float m2 = acc * acc;
            #pragma unroll
            for (int off = 32; off > 0; off >>= 1) m2 += __shfl_xor(m2, off, 64);
            lam64 = sqrtf(m2);
            v = acc * (1.0f / lam64);
        }
        if (tid == 0) slam64 = lam64;
    }
    __syncthreads();

    const float x = 0.15f * exp2f(log2f(slam64) * (1.0f / 64.0f));
    float iv[4];
    {
        const float xh = 0.5f * x, xh2 = xh * xh;
        #pragma unroll
        for (int n = 0; n < 4; ++n) {
            float c = 1.0f;
            for (int q = 2; q <= n; ++q) c /= (float)q;
            float p = 1.0f;
            for (int q = 0; q < n; ++q) p *= xh;
            float s = 0.f;
            for (int k = 0; k < 25; ++k) {
                s += c * p;
                p *= xh2;
                c /= (float)((k + 1) * (k + 1 + n));
            }
            iv[n] = s;
        }
    }
    const float ex = expf(x), emx = expf(-x);
    #pragma unroll
    for (int pass = 0; pass < 2; ++pass) {
        const float a1 = pass ? (-2.f * emx * iv[1]) : (2.f * ex * iv[1]);
        const float a2 = pass ? ( 2.f * emx * iv[2]) : (2.f * ex * iv[2]);
        const float a3 = pass ? (-2.f * emx * iv[3]) : (2.f * ex * iv[3]);
        for (int s = tid; s < NN * 11; s += 256) {
            const int i = s / 11, q = s % 11;
            const float4 l4  = *reinterpret_cast<const float4*>(&sL[i][q * 4]);
            const float4 t24 = *reinterpret_cast<const float4*>(&sT2[i][q * 4]);
            const float4 t34 = *reinterpret_cast<const float4*>(&sT3[i][q * 4]);
            float4 w;
            w.x = fmaf(a1, l4.x, fmaf(a2, t24.x, a3 * t34.x));
            w.y = fmaf(a1, l4.y, fmaf(a2, t24.y, a3 * t34.y));
            w.z = fmaf(a1, l4.z, fmaf(a2, t24.z, a3 * t34.z));
            w.w = fmaf(a1, l4.w, fmaf(a2, t24.w, a3 * t34.w));
            w.x = (w.x < 1e-4f) ? 0.f : w.x;  w.y = (w.y < 1e-4f) ? 0.f : w.y;
            w.z = (w.z < 1e-4f) ? 0.f : w.z;  w.w = (w.w < 1e-4f) ? 0.f : w.w;
            *reinterpret_cast<float4*>(&sG[i][q * 4]) = w;
        }
        __syncthreads();
        if (tid < NN) {
            float s = 0.f;
            #pragma unroll
            for (int q = 0; q < 11; ++q) {
                const float4 w4 = *reinterpret_cast<const float4*>(&sG[tid][q * 4]);
                s += fabsf(w4.x) + fabsf(w4.y) + fabsf(w4.z) + fabsf(w4.w);
            }
            srs[tid] = 1.0f / fmaxf(s, 1e-12f);
        }
        __syncthreads();
        if (pass == 0) {
            float* dst = WoT + (size_t)b * NN * NN;
            for (int e = tid; e < NN * NN; e += 256) {
                const int j = e / NN, i = e % NN;     // dst[j][i] = W[i][j]
                dst[e] = sG[i][j] * srs[i];
            }
        } else {
            float* dst = Wio + (size_t)b * NN * NN;
            for (int e = tid; e < NN * NN; e += 256) dst[e] = sG[e / NN][e % NN] * srs[e / NN];
        }
        __syncthreads();
    }
}

// ---------------------------------------------------------------------------
// Prep: split weights into hi/lo bf16, transposed fragment-friendly [n][k],
// padded to 288x288, three weights back to back.  Also coff = exp(lsv).
// ---------------------------------------------------------------------------
__global__ __launch_bounds__(256) void k_splitB(const float* __restrict__ gW,
                                                const float* __restrict__ W1,
                                                const float* __restrict__ W2,
                                                const float* __restrict__ lsv,
                                                unsigned short* __restrict__ Bth,
                                                unsigned short* __restrict__ Btl,
                                                float* __restrict__ coff)
{
    const int t = blockIdx.x * 256 + threadIdx.x;
    if (t < NN * DD) coff[t] = expf(lsv[t]);
    if (t >= 3 * DP * DP) return;
    const int w = t / (DP * DP);
    const int r = t % (DP * DP);
    const int n = r / DP, k = r % DP;
    const float* src = (w == 0) ? gW : ((w == 1) ? W1 : W2);
    const float v = (n < DD && k < DD) ? src[k * DD + n] : 0.0f;
    const unsigned short h = f2bf(v);
    Bth[t] = h;
    Btl[t] = f2bf(v - bf2f(h));
}

// ---------------------------------------------------------------------------
// Prep: split X [M][271] f32 -> hi/lo bf16 [M][288], zero-padded.
// ---------------------------------------------------------------------------
__global__ __launch_bounds__(256) void k_splitX(const float* __restrict__ X,
                                                unsigned short* __restrict__ Xhi,
                                                unsigned short* __restrict__ Xlo)
{
    const long long t = (long long)blockIdx.x * 256 + threadIdx.x;
    if (t >= MROWS * (DP / 8)) return;
    const long long m = t / (DP / 8);
    const int k0 = (int)(t % (DP / 8)) * 8;
    ushort8 h, l;
    #pragma unroll
    for (int j = 0; j < 8; ++j) {
        const int k = k0 + j;
        const float v = (k < DD) ? X[m * DD + k] : 0.0f;
        const unsigned short hh = f2bf(v);
        h[j] = hh;
        l[j] = f2bf(v - bf2f(hh));
    }
    *reinterpret_cast<ushort8*>(&Xhi[m * DP + k0]) = h;
    *reinterpret_cast<ushort8*>(&Xlo[m * DP + k0]) = l;
}

// ---------------------------------------------------------------------------
// MFMA GEMM: C[M,288] = act(A[M,288] @ B[288,288] + bias)
// BM=256, BN=96, BK=32; 4 waves, 16x16x32 bf16 MFMA, split-bf16 precision.
// OMODE: 0 = f32 out, 1 = split bf16 out, 2 = single bf16 out.
// ---------------------------------------------------------------------------
template<bool SPLITA, int OMODE>
__global__ __launch_bounds__(256) void k_gemm_mfma(
    const unsigned short* __restrict__ Ahi, const unsigned short* __restrict__ Alo,
    const unsigned short* __restrict__ Bth, const unsigned short* __restrict__ Btl,
    const float* __restrict__ bias, const int relu,
    float* __restrict__ outF, unsigned short* __restrict__ outHi,
    unsigned short* __restrict__ outLo)
{
    __shared__ __align__(16) unsigned short A_l[256 * 64];
    __shared__ __align__(16) unsigned short B_l[96 * 64];
    const int tid  = threadIdx.x;
    const int lane = tid & 63, w = tid >> 6;
    const long long row0 = (long long)blockIdx.x * 256;
    const int n0 = blockIdx.y * 96;

    f32x4 acc[4][6];
    #pragma unroll
    for (int mf = 0; mf < 4; ++mf)
        #pragma unroll
        for (int nf = 0; nf < 6; ++nf)
            acc[mf][nf] = (f32x4){0.f, 0.f, 0.f, 0.f};

    for (int kt = 0; kt < DP; kt += 32) {
        #pragma unroll
        for (int i = 0; i < 4; ++i) {
            const int q = tid + i * 256;
            const int m = q >> 2, c = q & 3;
            const long long g = (row0 + m) * DP + kt + c * 8;
            const ushort8 hv = *reinterpret_cast<const ushort8*>(Ahi + g);
            *reinterpret_cast<ushort8*>(&A_l[m * 64 + ((c ^ (m & 7)) * 8)]) = hv;
            if (SPLITA) {
                const ushort8 lv = *reinterpret_cast<const ushort8*>(Alo + g);
                *reinterpret_cast<ushort8*>(&A_l[m * 64 + (((c + 4) ^ (m & 7)) * 8)]) = lv;
            }
        }
        #pragma unroll
        for (int i = 0; i < 2; ++i) {
            const int q = tid + i * 256;
            if (q < 96 * 4) {
                const int n = q >> 2, c = q & 3;
                const long long g = (long long)(n0 + n) * DP + kt + c * 8;
                const ushort8 hv = *reinterpret_cast<const ushort8*>(Bth + g);
                const ushort8 lv = *reinterpret_cast<const ushort8*>(Btl + g);
                *reinterpret_cast<ushort8*>(&B_l[n * 64 + ((c ^ (n & 7)) * 8)]) = hv;
                *reinterpret_cast<ushort8*>(&B_l[n * 64 + (((c + 4) ^ (n & 7)) * 8)]) = lv;
            }
        }
        __syncthreads();

        const int cb = lane >> 4;
        short8 ah[4], al[4];
        #pragma unroll
        for (int mf = 0; mf < 4; ++mf) {
            const int m = w * 64 + mf * 16 + (lane & 15);
            ah[mf] = *reinterpret_cast<const short8*>(&A_l[m * 64 + ((cb ^ (m & 7)) * 8)]);
            if (SPLITA)
                al[mf] = *reinterpret_cast<const short8*>(&A_l[m * 64 + (((cb + 4) ^ (m & 7)) * 8)]);
        }
        #pragma unroll
        for (int nf = 0; nf < 6; ++nf) {
            const int n = nf * 16 + (lane & 15);
            const short8 bh = *reinterpret_cast<const short8*>(&B_l[n * 64 + ((cb ^ (n & 7)) * 8)]);
            const short8 bl = *reinterpret_cast<const short8*>(&B_l[n * 64 + (((cb + 4) ^ (n & 7)) * 8)]);
            #pragma unroll
            for (int mf = 0; mf < 4; ++mf) {
                acc[mf][nf] = __builtin_amdgcn_mfma_f32_16x16x32_bf16(ah[mf], bh, acc[mf][nf], 0, 0, 0);
                if (SPLITA)
                    acc[mf][nf] = __builtin_amdgcn_mfma_f32_16x16x32_bf16(al[mf], bh, acc[mf][nf], 0, 0, 0);
                acc[mf][nf] = __builtin_amdgcn_mfma_f32_16x16x32_bf16(ah[mf], bl, acc[mf][nf], 0, 0, 0);
            }
        }
        __syncthreads();
    }

    #pragma unroll
    for (int mf = 0; mf < 4; ++mf) {
        const long long rbase = row0 + w * 64 + mf * 16 + ((lane >> 4) * 4);
        #pragma unroll
        for (int nf = 0; nf < 6; ++nf) {
            const int col = n0 + nf * 16 + (lane & 15);
            const float bv = (bias && col < DD) ? bias[col] : 0.0f;
            #pragma unroll
            for (int r = 0; r < 4; ++r) {
                float v = acc[mf][nf][r] + bv;
                if (relu) v = fmaxf(v, 0.f);
                const long long idx = (rbase + r) * DP + col;
                if (OMODE == 0) {
                    outF[idx] = v;
                } else if (OMODE == 2) {
                    outHi[idx] = f2bf(v);
                } else {
                    const unsigned short h = f2bf(v);
                    outHi[idx] = h;
                    outLo[idx] = f2bf(v - bf2f(h));
                }
            }
        }
    }
}

// ---------------------------------------------------------------------------
// K3 v2: per-sample wavelet application, register-resident columns.
// Thread = one feature column c. h column (41) and out (41) in VGPRs;
// W^T / Wi / gk are wave-uniform -> scalar loads; inner loop = pure v_fmac.
//   out <- coff * relu( W @ (gk .* (Wi @ h)) ),  written as split bf16.
// ---------------------------------------------------------------------------
__global__ __launch_bounds__(320) void k_wavapply(const float* __restrict__ WT,
                                                  const float* __restrict__ Wi,
                                                  const float* __restrict__ gk,
                                                  const float* __restrict__ coff,
                                                  const float* __restrict__ h,
                                                  unsigned short* __restrict__ Ohi,
                                                  unsigned short* __restrict__ Olo)
{
    const int b = blockIdx.x;
    const int c = threadIdx.x;
    const bool act = (c < DD);
    const float* __restrict__ WTb = WT + (size_t)b * NN * NN;
    const float* __restrict__ Wib = Wi + (size_t)b * NN * NN;

    float hreg[NN];
    #pragma unroll
    for (int j = 0; j < NN; ++j)
        hreg[j] = act ? h[((size_t)b * NN + j) * DP + c] : 0.0f;

    float out[NN];
    #pragma unroll
    for (int i = 0; i < NN; ++i) out[i] = 0.0f;

    for (int j = 0; j < NN; ++j) {           // dynamic loop: I-cache friendly
        float tj = 0.f;
        #pragma unroll
        for (int k = 0; k < NN; ++k)         // Wi row j: uniform -> s_load
            tj = fmaf(Wib[j * NN + k], hreg[k], tj);
        tj *= gk[j];
        #pragma unroll
        for (int i = 0; i < NN; ++i)         // W col j (= WT row j): s_load
            out[i] = fmaf(WTb[j * NN + i], tj, out[i]);
    }

    if (act) {
        #pragma unroll
        for (int i = 0; i < NN; ++i) {
            const float o = fmaxf(out[i], 0.0f) * coff[i * DD + c];
            const long long idx = ((size_t)b * NN + i) * DP + c;
            const unsigned short hh = f2bf(o);
            Ohi[idx] = hh;
            Olo[idx] = f2bf(o - bf2f(hh));
        }
    }
}

// ---------------------------------------------------------------------------
__global__ __launch_bounds__(256) void k_mean(const float* __restrict__ fr, float* __restrict__ seq)
{
    const int b = blockIdx.x;
    for (int d = threadIdx.x; d < DD; d += 256) {
        float s = 0.f;
        #pragma unroll
        for (int n = 0; n < NN; ++n) s += fr[((size_t)b * NN + n) * DP + d];
        seq[(size_t)b * DD + d] = s * (1.0f / 41.0f);
    }
}

__global__ __launch_bounds__(256) void k_stats(const float* __restrict__ seq, float* __restrict__ stats)
{
    __shared__ float s1[256], s2[256];
    const int d = blockIdx.x;
    float a = 0.f, q = 0.f;
    for (int b = threadIdx.x; b < BB; b += 256) {
        float v = seq[(size_t)b * DD + d];
        a += v; q = fmaf(v, v, q);
    }
    s1[threadIdx.x] = a; s2[threadIdx.x] = q;
    __syncthreads();
    for (int o = 128; o > 0; o >>= 1) {
        if (threadIdx.x < o) { s1[threadIdx.x] += s1[threadIdx.x + o]; s2[threadIdx.x] += s2[threadIdx.x + o]; }
        __syncthreads();
    }
    if (threadIdx.x == 0) {
        float m = s1[0] * (1.0f / BB);
        float v = s2[0] * (1.0f / BB) - m * m;
        stats[d]      = m;
        stats[DD + d] = 1.0f / sqrtf(v + 1e-5f);
    }
}

__global__ __launch_bounds__(256) void k_bn(const float* __restrict__ seq, const float* __restrict__ stats,
                                            const float* __restrict__ g, const float* __restrict__ bt,
                                            float* __restrict__ out)
{
    const long long idx = (long long)blockIdx.x * 256 + threadIdx.x;
    if (idx < (long long)BB * DD) {
        const int d = (int)(idx % DD);
        out[idx] = (seq[idx] - stats[d]) * stats[DD + d] * g[d] + bt[d];
    }
}

// ---------------------------------------------------------------------------
extern "C" void kernel_launch(void* const* d_in, const int* in_sizes, int n_in,
                              void* d_out, int out_size, void* d_ws, size_t ws_size,
                              hipStream_t stream)
{
    const float* G   = (const float*)d_in[0];
    const float* X   = (const float*)d_in[1];
    const float* gk  = (const float*)d_in[2];
    const float* gW  = (const float*)d_in[3];
    const float* lsv = (const float*)d_in[4];
    const float* W1  = (const float*)d_in[5];
    const float* b1  = (const float*)d_in[6];
    const float* W2  = (const float*)d_in[7];
    const float* b2  = (const float*)d_in[8];
    const float* gam = (const float*)d_in[9];
    const float* bet = (const float*)d_in[10];

    char* p = (char*)d_ws;
    auto alloc = [&](size_t bytes) { void* r = (void*)p; p += (bytes + 255) & ~(size_t)255; return r; };
    const size_t MD  = (size_t)MROWS * DP;
    float*          WwavT = (float*)alloc((size_t)BB * NN * NN * 4);
    float*          Wiwav = (float*)alloc((size_t)BB * NN * NN * 4);
    unsigned short* Shi   = (unsigned short*)alloc(MD * 2);
    unsigned short* Slo   = (unsigned short*)alloc(MD * 2);
    float*          bufA  = (float*)alloc(MD * 4);
    unsigned short* P2    = (unsigned short*)alloc(MD * 2);
    unsigned short* Bth   = (unsigned short*)alloc((size_t)3 * DP * DP * 2);
    unsigned short* Btl   = (unsigned short*)alloc((size_t)3 * DP * DP * 2);
    float*          coff  = (float*)alloc((size_t)NN * DD * 4);
    float*          seq   = (float*)alloc((size_t)BB * DD * 4);
    float*          stats = (float*)alloc(2 * DD * 4);

    const int WB = DP * DP;

    k_wavelet<<<BB, 256, 0, stream>>>(G, WwavT, Wiwav);
    k_splitB<<<(3 * DP * DP + 255) / 256, 256, 0, stream>>>(gW, W1, W2, lsv, Bth, Btl, coff);
    k_splitX<<<(unsigned)((MROWS * (DP / 8) + 255) / 256), 256, 0, stream>>>(X, Shi, Slo);

    dim3 ggrid((unsigned)(MROWS / 256), 3);
    // GEMM1: h = X @ gW          (split A, f32 out)
    k_gemm_mfma<true, 0><<<ggrid, 256, 0, stream>>>(Shi, Slo, Bth, Btl, nullptr, 0,
                                                    bufA, nullptr, nullptr);
    // wavelet apply: bufA -> split bf16 into Shi/Slo
    k_wavapply<<<BB, 320, 0, stream>>>(WwavT, Wiwav, gk, coff, bufA, Shi, Slo);
    // GEMM2: relu(. @ W1 + b1)   (split A, single-bf16 out)
    k_gemm_mfma<true, 2><<<ggrid, 256, 0, stream>>>(Shi, Slo, Bth + WB, Btl + WB, b1, 1,
                                                    nullptr, P2, nullptr);
    // GEMM3: . @ W2 + b2         (single A, f32 out)
    k_gemm_mfma<false, 0><<<ggrid, 256, 0, stream>>>(P2, nullptr, Bth + 2 * WB, Btl + 2 * WB, b2, 0,
                                                     bufA, nullptr, nullptr);
    k_mean<<<BB, 256, 0, stream>>>(bufA, seq);
    k_stats<<<DD, 256, 0, stream>>>(seq, stats);
    k_bn<<<(unsigned)(((long long)BB * DD + 255) / 256), 256, 0, stream>>>(seq, stats, gam, bet, (float*)d_out);
}

// Round 5
// 1116.396 us; speedup vs baseline: 2.7553x; 1.0248x over previous
//
#include <hip/hip_runtime.h>
#include <math.h>

namespace {
constexpr int BB = 4096;   // batch
constexpr int NN = 41;     // nodes
constexpr int DD = 271;    // features
constexpr int DP = 288;    // padded feature dim (multiple of 32)
constexpr int PW = 44;     // padded row stride for 41-wide LDS matrices
constexpr long long MROWS = (long long)BB * NN;   // 167936
}

typedef __attribute__((ext_vector_type(8))) unsigned short ushort8;
typedef __attribute__((ext_vector_type(8))) short          short8;
typedef __attribute__((ext_vector_type(4))) float          f32x4;

__device__ __forceinline__ unsigned short f2bf(float f) {
    unsigned u = __float_as_uint(f);
    unsigned r = (u + 0x7FFFu + ((u >> 16) & 1u)) >> 16;
    return (unsigned short)r;
}
__device__ __forceinline__ float bf2f(unsigned short h) {
    return __uint_as_float(((unsigned)h) << 16);
}

// ---------------------------------------------------------------------------
// LDS matmul helper: C = scale * A@B - (sub ? sub : 0), 41x41, stride-44 rows.
// ---------------------------------------------------------------------------
__device__ __forceinline__ void lds_mm(const float (*__restrict__ A)[PW],
                                       const float (*__restrict__ B)[PW],
                                       float (*__restrict__ C)[PW],
                                       const float scale,
                                       const float (*__restrict__ sub)[PW],
                                       const int tid)
{
    for (int s = tid; s < NN * 11; s += 256) {
        const int i = s / 11, q = s % 11;
        float4 acc = make_float4(0.f, 0.f, 0.f, 0.f);
        #pragma unroll
        for (int k = 0; k < NN; ++k) {
            const float a = A[i][k];
            const float4 b4 = *reinterpret_cast<const float4*>(&B[k][q * 4]);
            acc.x = fmaf(a, b4.x, acc.x); acc.y = fmaf(a, b4.y, acc.y);
            acc.z = fmaf(a, b4.z, acc.z); acc.w = fmaf(a, b4.w, acc.w);
        }
        float4 r;
        if (sub) {
            const float4 s4 = *reinterpret_cast<const float4*>(&sub[i][q * 4]);
            r = make_float4(fmaf(scale, acc.x, -s4.x), fmaf(scale, acc.y, -s4.y),
                            fmaf(scale, acc.z, -s4.z), fmaf(scale, acc.w, -s4.w));
        } else {
            r = make_float4(scale * acc.x, scale * acc.y, scale * acc.z, scale * acc.w);
        }
        *reinterpret_cast<float4*>(&C[i][q * 4]) = r;
    }
}

// ---------------------------------------------------------------------------
// K1: wavelet basis -> fused M = l1n(thr(W)) @ diag(gk) @ l1n(thr(Wi)).
// Output: MT[b][j][i] = M[b][i][j] (transposed, so M columns are contiguous
// rows for k_wavX's scalar loads).
// ---------------------------------------------------------------------------
__global__ __launch_bounds__(256) void k_wavelet(const float* __restrict__ G,
                                                 const float* __restrict__ gk,
                                                 float* __restrict__ MT)
{
    __shared__ float sG[NN][PW];    // G -> squaring ping -> Win scratch
    __shared__ float sL[NN][PW];    // L -> final M
    __shared__ float sT2[NN][PW];
    __shared__ float sT3[NN][PW];
    __shared__ float sM[NN][PW];    // squaring pong -> L^64 -> Wn
    __shared__ float sdeg[NN], sdinv[NN], srs[NN];
    __shared__ float slam64;

    const int b   = blockIdx.x;
    const int tid = threadIdx.x;
    const float* Gb = G + (size_t)b * NN * NN;

    for (int e = tid; e < NN * PW; e += 256) {
        const int i = e / PW, j = e % PW;
        sG[i][j] = (j < NN) ? Gb[i * NN + j] : 0.0f;
    }
    __syncthreads();

    if (tid < NN) {
        float4 s4 = make_float4(0.f, 0.f, 0.f, 0.f);
        #pragma unroll
        for (int q = 0; q < 11; ++q) {
            const float4 g4 = *reinterpret_cast<const float4*>(&sG[tid][q * 4]);
            s4.x += g4.x; s4.y += g4.y; s4.z += g4.z; s4.w += g4.w;
        }
        const float s = (s4.x + s4.y) + (s4.z + s4.w);
        sdeg[tid]  = s;
        sdinv[tid] = 1.0f / (sqrtf(s) + 1e-6f);
    }
    __syncthreads();

    for (int e = tid; e < NN * PW; e += 256) {
        const int i = e / PW, j = e % PW;
        if (j < NN) {
            const float a = 0.5f * (sG[i][j] + sG[j][i]);
            const float v = ((i == j) ? sdeg[i] : 0.0f) - a;
            sL[i][j] = sdinv[i] * sdinv[j] * v;
        } else {
            sL[i][j] = 0.0f;
        }
    }
    __syncthreads();

    lds_mm(sL, sL, sT2, 2.0f, nullptr, tid);   // T2 = 2 L^2
    __syncthreads();
    lds_mm(sL, sT2, sT3, 2.0f, sL, tid);       // T3 = 2 L T2 - L
    __syncthreads();

    // lambda_max via matrix squaring to L^64 + 4 matvec iterations
    lds_mm(sT2, sT2, sM, 0.25f, nullptr, tid); // L^4
    __syncthreads();
    lds_mm(sM, sM, sG, 1.0f, nullptr, tid);    // L^8
    __syncthreads();
    lds_mm(sG, sG, sM, 1.0f, nullptr, tid);    // L^16
    __syncthreads();
    lds_mm(sM, sM, sG, 1.0f, nullptr, tid);    // L^32
    __syncthreads();
    lds_mm(sG, sG, sM, 1.0f, nullptr, tid);    // L^64
    __syncthreads();

    if (tid < 64) {
        float lr[NN];
        #pragma unroll
        for (int j = 0; j < NN; ++j) lr[j] = (tid < NN) ? sM[tid][j] : 0.0f;
        unsigned h = (unsigned)(tid + 1) * 2654435761u;
        h ^= h >> 13; h *= 0x85ebca6bu; h ^= h >> 16;
        float v = (tid < NN) ? (0.25f + (float)(h & 1023) * (1.0f / 1024.0f)) : 0.0f;
        float n2 = v * v;
        #pragma unroll
        for (int off = 32; off > 0; off >>= 1) n2 += __shfl_xor(n2, off, 64);
        v *= rsqrtf(n2);
        float lam64 = 1.0f;
        #pragma unroll
        for (int it = 0; it < 4; ++it) {
            float acc = 0.f;
            #pragma unroll
            for (int j = 0; j < NN; ++j) acc = fmaf(lr[j], __shfl(v, j, 64), acc);
            float m2 = acc * acc;
            #pragma unroll
            for (int off = 32; off > 0; off >>= 1) m2 += __shfl_xor(m2, off, 64);
            lam64 = sqrtf(m2);
            v = acc * (1.0f / lam64);
        }
        if (tid == 0) slam64 = lam64;
    }
    __syncthreads();

    const float x = 0.15f * exp2f(log2f(slam64) * (1.0f / 64.0f));
    float iv[4];
    {
        const float xh = 0.5f * x, xh2 = xh * xh;
        #pragma unroll
        for (int n = 0; n < 4; ++n) {
            float c = 1.0f;
            for (int q = 2; q <= n; ++q) c /= (float)q;
            float p = 1.0f;
            for (int q = 0; q < n; ++q) p *= xh;
            float s = 0.f;
            for (int k = 0; k < 25; ++k) {
                s += c * p;
                p *= xh2;
                c /= (float)((k + 1) * (k + 1 + n));
            }
            iv[n] = s;
        }
    }
    const float ex = expf(x), emx = expf(-x);

    // --- Wn = l1norm(thresh(W)) -> sM  (sM free after lambda) ---
    {
        const float a1 = 2.f * ex * iv[1], a2 = 2.f * ex * iv[2], a3 = 2.f * ex * iv[3];
        for (int s = tid; s < NN * 11; s += 256) {
            const int i = s / 11, q = s % 11;
            const float4 l4  = *reinterpret_cast<const float4*>(&sL[i][q * 4]);
            const float4 t24 = *reinterpret_cast<const float4*>(&sT2[i][q * 4]);
            const float4 t34 = *reinterpret_cast<const float4*>(&sT3[i][q * 4]);
            float4 w;
            w.x = fmaf(a1, l4.x, fmaf(a2, t24.x, a3 * t34.x));
            w.y = fmaf(a1, l4.y, fmaf(a2, t24.y, a3 * t34.y));
            w.z = fmaf(a1, l4.z, fmaf(a2, t24.z, a3 * t34.z));
            w.w = fmaf(a1, l4.w, fmaf(a2, t24.w, a3 * t34.w));
            w.x = (w.x < 1e-4f) ? 0.f : w.x;  w.y = (w.y < 1e-4f) ? 0.f : w.y;
            w.z = (w.z < 1e-4f) ? 0.f : w.z;  w.w = (w.w < 1e-4f) ? 0.f : w.w;
            *reinterpret_cast<float4*>(&sM[i][q * 4]) = w;
        }
        __syncthreads();
        if (tid < NN) {
            float s = 0.f;
            #pragma unroll
            for (int q = 0; q < 11; ++q) {
                const float4 w4 = *reinterpret_cast<const float4*>(&sM[tid][q * 4]);
                s += fabsf(w4.x) + fabsf(w4.y) + fabsf(w4.z) + fabsf(w4.w);
            }
            srs[tid] = 1.0f / fmaxf(s, 1e-12f);
        }
        __syncthreads();
    }
    // --- scale Wn rows in place; Win = thresh(Wi) -> sG (independent bufs) ---
    {
        const float a1 = -2.f * emx * iv[1], a2 = 2.f * emx * iv[2], a3 = -2.f * emx * iv[3];
        for (int s = tid; s < NN * 11; s += 256) {
            const int i = s / 11, q = s % 11;
            // scale Wn
            float4 m4 = *reinterpret_cast<float4*>(&sM[i][q * 4]);
            const float rs = srs[i];
            m4.x *= rs; m4.y *= rs; m4.z *= rs; m4.w *= rs;
            *reinterpret_cast<float4*>(&sM[i][q * 4]) = m4;
            // combine Wi
            const float4 l4  = *reinterpret_cast<const float4*>(&sL[i][q * 4]);
            const float4 t24 = *reinterpret_cast<const float4*>(&sT2[i][q * 4]);
            const float4 t34 = *reinterpret_cast<const float4*>(&sT3[i][q * 4]);
            float4 w;
            w.x = fmaf(a1, l4.x, fmaf(a2, t24.x, a3 * t34.x));
            w.y = fmaf(a1, l4.y, fmaf(a2, t24.y, a3 * t34.y));
            w.z = fmaf(a1, l4.z, fmaf(a2, t24.z, a3 * t34.z));
            w.w = fmaf(a1, l4.w, fmaf(a2, t24.w, a3 * t34.w));
            w.x = (w.x < 1e-4f) ? 0.f : w.x;  w.y = (w.y < 1e-4f) ? 0.f : w.y;
            w.z = (w.z < 1e-4f) ? 0.f : w.z;  w.w = (w.w < 1e-4f) ? 0.f : w.w;
            *reinterpret_cast<float4*>(&sG[i][q * 4]) = w;
        }
        __syncthreads();
        if (tid < NN) {
            float s = 0.f;
            #pragma unroll
            for (int q = 0; q < 11; ++q) {
                const float4 w4 = *reinterpret_cast<const float4*>(&sG[tid][q * 4]);
                s += fabsf(w4.x) + fabsf(w4.y) + fabsf(w4.z) + fabsf(w4.w);
            }
            sdeg[tid] = gk[tid] / fmaxf(s, 1e-12f);   // row scale incl. kernel
        }
        __syncthreads();
        for (int s = tid; s < NN * 11; s += 256) {
            const int j = s / 11, q = s % 11;
            float4 w4 = *reinterpret_cast<float4*>(&sG[j][q * 4]);
            const float rs = sdeg[j];
            w4.x *= rs; w4.y *= rs; w4.z *= rs; w4.w *= rs;
            *reinterpret_cast<float4*>(&sG[j][q * 4]) = w4;
        }
        __syncthreads();
    }
    // --- M = Wn @ (diag(gk) Win) -> sL; write transposed ---
    lds_mm(sM, sG, sL, 1.0f, nullptr, tid);
    __syncthreads();
    float* dst = MT + (size_t)b * NN * NN;
    for (int e = tid; e < NN * NN; e += 256) {
        const int j = e / NN, i = e % NN;
        dst[e] = sL[i][j];
    }
}

// ---------------------------------------------------------------------------
// Prep: split weights into hi/lo bf16, transposed [n][k], padded 288x288,
// three weights back to back. Also coff = exp(lsv).
// ---------------------------------------------------------------------------
__global__ __launch_bounds__(256) void k_splitB(const float* __restrict__ gW,
                                                const float* __restrict__ W1,
                                                const float* __restrict__ W2,
                                                const float* __restrict__ lsv,
                                                unsigned short* __restrict__ Bth,
                                                unsigned short* __restrict__ Btl,
                                                float* __restrict__ coff)
{
    const int t = blockIdx.x * 256 + threadIdx.x;
    if (t < NN * DD) coff[t] = expf(lsv[t]);
    if (t >= 3 * DP * DP) return;
    const int w = t / (DP * DP);
    const int r = t % (DP * DP);
    const int n = r / DP, k = r % DP;
    const float* src = (w == 0) ? gW : ((w == 1) ? W1 : W2);
    const float v = (n < DD && k < DD) ? src[k * DD + n] : 0.0f;
    const unsigned short h = f2bf(v);
    Bth[t] = h;
    Btl[t] = f2bf(v - bf2f(h));
}

// ---------------------------------------------------------------------------
// K2: Y = M @ X per sample, written as split bf16 [M][288] zero-padded.
// Thread = feature column. out[41] register-resident, j-outer streaming X:
// 41 INDEPENDENT fmas per step (no serial chain), M rows via scalar loads.
// ---------------------------------------------------------------------------
__global__ __launch_bounds__(320) void k_wavX(const float* __restrict__ MT,
                                              const float* __restrict__ X,
                                              unsigned short* __restrict__ Yhi,
                                              unsigned short* __restrict__ Ylo)
{
    const int b = blockIdx.x;
    const int c = threadIdx.x;
    const float* __restrict__ Mb = MT + (size_t)b * NN * NN;
    const bool rd = (c < DD);

    float out[NN];
    #pragma unroll
    for (int i = 0; i < NN; ++i) out[i] = 0.f;

    for (int j = 0; j < NN; ++j) {
        const float xj = rd ? X[((size_t)b * NN + j) * DD + c] : 0.0f;
        const float* __restrict__ Mrow = Mb + j * NN;   // uniform -> s_load
        #pragma unroll
        for (int i = 0; i < NN; ++i)
            out[i] = fmaf(Mrow[i], xj, out[i]);
    }

    if (c < DP) {
        #pragma unroll
        for (int i = 0; i < NN; ++i) {
            const long long idx = ((size_t)b * NN + i) * DP + c;
            const unsigned short hh = f2bf(out[i]);
            Yhi[idx] = hh;
            Ylo[idx] = f2bf(out[i] - bf2f(hh));
        }
    }
}

// ---------------------------------------------------------------------------
// MFMA GEMM: C[M,288] = act(A[M,288] @ B[288,288] + bias)
// BM=256, BN=96, BK=32; 4 waves, 16x16x32 bf16 MFMA, split-bf16 precision.
// OMODE: 0 = f32 out (+bias), 1 = relu*coff[node,col] split-bf16 out,
//        2 = relu(+bias) single-bf16 out.
// ---------------------------------------------------------------------------
template<bool SPLITA, int OMODE>
__global__ __launch_bounds__(256) void k_gemm_mfma(
    const unsigned short* __restrict__ Ahi, const unsigned short* __restrict__ Alo,
    const unsigned short* __restrict__ Bth, const unsigned short* __restrict__ Btl,
    const float* __restrict__ bias, const int relu, const float* __restrict__ coff,
    float* __restrict__ outF, unsigned short* __restrict__ outHi,
    unsigned short* __restrict__ outLo)
{
    __shared__ __align__(16) unsigned short A_l[256 * 64];
    __shared__ __align__(16) unsigned short B_l[96 * 64];
    const int tid  = threadIdx.x;
    const int lane = tid & 63, w = tid >> 6;
    const long long row0 = (long long)blockIdx.x * 256;
    const int n0 = blockIdx.y * 96;

    f32x4 acc[4][6];
    #pragma unroll
    for (int mf = 0; mf < 4; ++mf)
        #pragma unroll
        for (int nf = 0; nf < 6; ++nf)
            acc[mf][nf] = (f32x4){0.f, 0.f, 0.f, 0.f};

    for (int kt = 0; kt < DP; kt += 32) {
        #pragma unroll
        for (int i = 0; i < 4; ++i) {
            const int q = tid + i * 256;
            const int m = q >> 2, c = q & 3;
            const long long g = (row0 + m) * DP + kt + c * 8;
            const ushort8 hv = *reinterpret_cast<const ushort8*>(Ahi + g);
            *reinterpret_cast<ushort8*>(&A_l[m * 64 + ((c ^ (m & 7)) * 8)]) = hv;
            if (SPLITA) {
                const ushort8 lv = *reinterpret_cast<const ushort8*>(Alo + g);
                *reinterpret_cast<ushort8*>(&A_l[m * 64 + (((c + 4) ^ (m & 7)) * 8)]) = lv;
            }
        }
        #pragma unroll
        for (int i = 0; i < 2; ++i) {
            const int q = tid + i * 256;
            if (q < 96 * 4) {
                const int n = q >> 2, c = q & 3;
                const long long g = (long long)(n0 + n) * DP + kt + c * 8;
                const ushort8 hv = *reinterpret_cast<const ushort8*>(Bth + g);
                const ushort8 lv = *reinterpret_cast<const ushort8*>(Btl + g);
                *reinterpret_cast<ushort8*>(&B_l[n * 64 + ((c ^ (n & 7)) * 8)]) = hv;
                *reinterpret_cast<ushort8*>(&B_l[n * 64 + (((c + 4) ^ (n & 7)) * 8)]) = lv;
            }
        }
        __syncthreads();

        const int cb = lane >> 4;
        short8 ah[4], al[4];
        #pragma unroll
        for (int mf = 0; mf < 4; ++mf) {
            const int m = w * 64 + mf * 16 + (lane & 15);
            ah[mf] = *reinterpret_cast<const short8*>(&A_l[m * 64 + ((cb ^ (m & 7)) * 8)]);
            if (SPLITA)
                al[mf] = *reinterpret_cast<const short8*>(&A_l[m * 64 + (((cb + 4) ^ (m & 7)) * 8)]);
        }
        #pragma unroll
        for (int nf = 0; nf < 6; ++nf) {
            const int n = nf * 16 + (lane & 15);
            const short8 bh = *reinterpret_cast<const short8*>(&B_l[n * 64 + ((cb ^ (n & 7)) * 8)]);
            const short8 bl = *reinterpret_cast<const short8*>(&B_l[n * 64 + (((cb + 4) ^ (n & 7)) * 8)]);
            #pragma unroll
            for (int mf = 0; mf < 4; ++mf) {
                acc[mf][nf] = __builtin_amdgcn_mfma_f32_16x16x32_bf16(ah[mf], bh, acc[mf][nf], 0, 0, 0);
                if (SPLITA)
                    acc[mf][nf] = __builtin_amdgcn_mfma_f32_16x16x32_bf16(al[mf], bh, acc[mf][nf], 0, 0, 0);
                acc[mf][nf] = __builtin_amdgcn_mfma_f32_16x16x32_bf16(ah[mf], bl, acc[mf][nf], 0, 0, 0);
            }
        }
        __syncthreads();
    }

    #pragma unroll
    for (int mf = 0; mf < 4; ++mf) {
        const long long rbase = row0 + w * 64 + mf * 16 + ((lane >> 4) * 4);
        #pragma unroll
        for (int nf = 0; nf < 6; ++nf) {
            const int col = n0 + nf * 16 + (lane & 15);
            const float bv = (OMODE != 1 && bias && col < DD) ? bias[col] : 0.0f;
            #pragma unroll
            for (int r = 0; r < 4; ++r) {
                float v = acc[mf][nf][r] + bv;
                if (relu) v = fmaxf(v, 0.f);
                const long long idx = (rbase + r) * DP + col;
                if (OMODE == 0) {
                    outF[idx] = v;
                } else if (OMODE == 2) {
                    outHi[idx] = f2bf(v);
                } else {
                    const unsigned nmod = (unsigned)(rbase + r) % 41u;   // node idx
                    const float cf = (col < DD) ? coff[nmod * DD + col] : 0.0f;
                    v *= cf;
                    const unsigned short h = f2bf(v);
                    outHi[idx] = h;
                    outLo[idx] = f2bf(v - bf2f(h));
                }
            }
        }
    }
}

// ---------------------------------------------------------------------------
// K5: per-sample node-mean of P2 (bf16) -> split bf16 mp2 [B][288].
// (mean commutes with the final Linear: seq = mean(P2) @ W2 + b2)
// ---------------------------------------------------------------------------
__global__ __launch_bounds__(320) void k_meanP2(const unsigned short* __restrict__ P2,
                                                unsigned short* __restrict__ Mhi,
                                                unsigned short* __restrict__ Mlo)
{
    const int b = blockIdx.x;
    const int c = threadIdx.x;
    if (c >= DP) return;
    float s = 0.f;
    #pragma unroll
    for (int n = 0; n < NN; ++n)
        s += bf2f(P2[((size_t)b * NN + n) * DP + c]);
    s *= (1.0f / 41.0f);
    const unsigned short hh = f2bf(s);
    Mhi[(size_t)b * DP + c] = hh;
    Mlo[(size_t)b * DP + c] = f2bf(s - bf2f(hh));
}

// ---------------------------------------------------------------------------
__global__ __launch_bounds__(256) void k_stats(const float* __restrict__ seq, float* __restrict__ stats)
{
    __shared__ float s1[256], s2[256];
    const int d = blockIdx.x;
    float a = 0.f, q = 0.f;
    for (int b = threadIdx.x; b < BB; b += 256) {
        float v = seq[(size_t)b * DP + d];
        a += v; q = fmaf(v, v, q);
    }
    s1[threadIdx.x] = a; s2[threadIdx.x] = q;
    __syncthreads();
    for (int o = 128; o > 0; o >>= 1) {
        if (threadIdx.x < o) { s1[threadIdx.x] += s1[threadIdx.x + o]; s2[threadIdx.x] += s2[threadIdx.x + o]; }
        __syncthreads();
    }
    if (threadIdx.x == 0) {
        float m = s1[0] * (1.0f / BB);
        float v = s2[0] * (1.0f / BB) - m * m;
        stats[d]      = m;
        stats[DD + d] = 1.0f / sqrtf(v + 1e-5f);
    }
}

__global__ __launch_bounds__(256) void k_bn(const float* __restrict__ seq, const float* __restrict__ stats,
                                            const float* __restrict__ g, const float* __restrict__ bt,
                                            float* __restrict__ out)
{
    const long long idx = (long long)blockIdx.x * 256 + threadIdx.x;
    if (idx < (long long)BB * DD) {
        const int d = (int)(idx % DD);
        const long long b = idx / DD;
        out[idx] = (seq[b * DP + d] - stats[d]) * stats[DD + d] * g[d] + bt[d];
    }
}

// ---------------------------------------------------------------------------
extern "C" void kernel_launch(void* const* d_in, const int* in_sizes, int n_in,
                              void* d_out, int out_size, void* d_ws, size_t ws_size,
                              hipStream_t stream)
{
    const float* G   = (const float*)d_in[0];
    const float* X   = (const float*)d_in[1];
    const float* gk  = (const float*)d_in[2];
    const float* gW  = (const float*)d_in[3];
    const float* lsv = (const float*)d_in[4];
    const float* W1  = (const float*)d_in[5];
    const float* b1  = (const float*)d_in[6];
    const float* W2  = (const float*)d_in[7];
    const float* b2  = (const float*)d_in[8];
    const float* gam = (const float*)d_in[9];
    const float* bet = (const float*)d_in[10];

    char* p = (char*)d_ws;
    auto alloc = [&](size_t bytes) { void* r = (void*)p; p += (bytes + 255) & ~(size_t)255; return r; };
    const size_t MD = (size_t)MROWS * DP;
    float*          MT    = (float*)alloc((size_t)BB * NN * NN * 4);      // 27.5 MB
    unsigned short* Yhi   = (unsigned short*)alloc(MD * 2);               // 96.7 MB
    unsigned short* Ylo   = (unsigned short*)alloc(MD * 2);
    unsigned short* Shi   = (unsigned short*)alloc(MD * 2);
    unsigned short* Slo   = (unsigned short*)alloc(MD * 2);
    unsigned short* P2    = (unsigned short*)alloc(MD * 2);
    unsigned short* Bth   = (unsigned short*)alloc((size_t)3 * DP * DP * 2);
    unsigned short* Btl   = (unsigned short*)alloc((size_t)3 * DP * DP * 2);
    float*          coff  = (float*)alloc((size_t)NN * DD * 4);
    unsigned short* mp2hi = (unsigned short*)alloc((size_t)BB * DP * 2);
    unsigned short* mp2lo = (unsigned short*)alloc((size_t)BB * DP * 2);
    float*          seqF  = (float*)alloc((size_t)BB * DP * 4);
    float*          stats = (float*)alloc(2 * DD * 4);

    const int WB = DP * DP;

    k_wavelet<<<BB, 256, 0, stream>>>(G, gk, MT);
    k_splitB<<<(3 * DP * DP + 255) / 256, 256, 0, stream>>>(gW, W1, W2, lsv, Bth, Btl, coff);
    k_wavX<<<BB, 320, 0, stream>>>(MT, X, Yhi, Ylo);

    dim3 ggrid((unsigned)(MROWS / 256), 3);
    // GEMM1: S = coff * relu((M@X) @ gW)   (split A, coff-relu split-bf16 out)
    k_gemm_mfma<true, 1><<<ggrid, 256, 0, stream>>>(Yhi, Ylo, Bth, Btl, nullptr, 1, coff,
                                                    nullptr, Shi, Slo);
    // GEMM2: P2 = relu(S @ W1 + b1)        (split A, single-bf16 out)
    k_gemm_mfma<true, 2><<<ggrid, 256, 0, stream>>>(Shi, Slo, Bth + WB, Btl + WB, b1, 1, nullptr,
                                                    nullptr, P2, nullptr);
    // node-mean of P2 (commutes with W2)
    k_meanP2<<<BB, 320, 0, stream>>>(P2, mp2hi, mp2lo);
    // GEMM3 (small, 4096 rows): seq = mean(P2) @ W2 + b2
    k_gemm_mfma<true, 0><<<dim3(BB / 256, 3), 256, 0, stream>>>(mp2hi, mp2lo, Bth + 2 * WB, Btl + 2 * WB,
                                                                b2, 0, nullptr, seqF, nullptr, nullptr);
    k_stats<<<DD, 256, 0, stream>>>(seqF, stats);
    k_bn<<<(unsigned)(((long long)BB * DD + 255) / 256), 256, 0, stream>>>(seqF, stats, gam, bet, (float*)d_out);
}

// Round 6
// 791.968 us; speedup vs baseline: 3.8840x; 1.4096x over previous
//
#include <hip/hip_runtime.h>
#include <math.h>

namespace {
constexpr int BB = 4096;   // batch
constexpr int NN = 41;     // nodes
constexpr int DD = 271;    // features
constexpr int DP = 288;    // padded feature dim (multiple of 32)
constexpr int PW = 44;     // padded row stride for 41-wide LDS matrices
constexpr long long MROWS = (long long)BB * NN;   // 167936
constexpr int AST = DP * 2;          // 576 ushorts per interleaved-split row
constexpr int WBE = DP * AST;        // per-weight Bint element stride
}

typedef __attribute__((ext_vector_type(8))) unsigned short ushort8;
typedef __attribute__((ext_vector_type(8))) short          short8;
typedef __attribute__((ext_vector_type(4))) float          f32x4;

__device__ __forceinline__ unsigned short f2bf(float f) {
    unsigned u = __float_as_uint(f);
    unsigned r = (u + 0x7FFFu + ((u >> 16) & 1u)) >> 16;
    return (unsigned short)r;
}
__device__ __forceinline__ float bf2f(unsigned short h) {
    return __uint_as_float(((unsigned)h) << 16);
}

// write one f32 value as split hi/lo bf16 into the interleaved-swizzled
// layout: row stride 576 ushorts; per 32-k group: 8 chunks of 8 ushorts,
// chunk index XOR-swizzled by (row & 7). hi chunks 0..3, lo 4..7.
__device__ __forceinline__ void store_split(unsigned short* __restrict__ dst,
                                            long long row, int col, float v)
{
    const unsigned short hh = f2bf(v);
    const unsigned short ll = f2bf(v - bf2f(hh));
    const long long base = row * AST + (col >> 5) * 64;
    const int cn = (col & 31) >> 3, k7 = col & 7, sw = (int)(row & 7);
    dst[base + ((cn ^ sw) << 3) + k7]       = hh;
    dst[base + (((cn + 4) ^ sw) << 3) + k7] = ll;
}

// ---------------------------------------------------------------------------
// LDS matmul helper: C = scale * A@B - (sub ? sub : 0), 41x41, stride-44 rows.
// ---------------------------------------------------------------------------
__device__ __forceinline__ void lds_mm(const float (*__restrict__ A)[PW],
                                       const float (*__restrict__ B)[PW],
                                       float (*__restrict__ C)[PW],
                                       const float scale,
                                       const float (*__restrict__ sub)[PW],
                                       const int tid)
{
    for (int s = tid; s < NN * 11; s += 256) {
        const int i = s / 11, q = s % 11;
        float4 acc = make_float4(0.f, 0.f, 0.f, 0.f);
        #pragma unroll
        for (int k = 0; k < NN; ++k) {
            const float a = A[i][k];
            const float4 b4 = *reinterpret_cast<const float4*>(&B[k][q * 4]);
            acc.x = fmaf(a, b4.x, acc.x); acc.y = fmaf(a, b4.y, acc.y);
            acc.z = fmaf(a, b4.z, acc.z); acc.w = fmaf(a, b4.w, acc.w);
        }
        float4 r;
        if (sub) {
            const float4 s4 = *reinterpret_cast<const float4*>(&sub[i][q * 4]);
            r = make_float4(fmaf(scale, acc.x, -s4.x), fmaf(scale, acc.y, -s4.y),
                            fmaf(scale, acc.z, -s4.z), fmaf(scale, acc.w, -s4.w));
        } else {
            r = make_float4(scale * acc.x, scale * acc.y, scale * acc.z, scale * acc.w);
        }
        *reinterpret_cast<float4*>(&C[i][q * 4]) = r;
    }
}

// ---------------------------------------------------------------------------
// K1: wavelet basis -> fused M = l1n(thr(W)) @ diag(gk) @ l1n(thr(Wi)).
// Output transposed: MT[b][j][i] = M[b][i][j].
// ---------------------------------------------------------------------------
__global__ __launch_bounds__(256) void k_wavelet(const float* __restrict__ G,
                                                 const float* __restrict__ gk,
                                                 float* __restrict__ MT)
{
    __shared__ float sG[NN][PW];
    __shared__ float sL[NN][PW];
    __shared__ float sT2[NN][PW];
    __shared__ float sT3[NN][PW];
    __shared__ float sM[NN][PW];
    __shared__ float sdeg[NN], sdinv[NN], srs[NN];
    __shared__ float slam64;

    const int b   = blockIdx.x;
    const int tid = threadIdx.x;
    const float* Gb = G + (size_t)b * NN * NN;

    for (int e = tid; e < NN * PW; e += 256) {
        const int i = e / PW, j = e % PW;
        sG[i][j] = (j < NN) ? Gb[i * NN + j] : 0.0f;
    }
    __syncthreads();

    if (tid < NN) {
        float4 s4 = make_float4(0.f, 0.f, 0.f, 0.f);
        #pragma unroll
        for (int q = 0; q < 11; ++q) {
            const float4 g4 = *reinterpret_cast<const float4*>(&sG[tid][q * 4]);
            s4.x += g4.x; s4.y += g4.y; s4.z += g4.z; s4.w += g4.w;
        }
        const float s = (s4.x + s4.y) + (s4.z + s4.w);
        sdeg[tid]  = s;
        sdinv[tid] = 1.0f / (sqrtf(s) + 1e-6f);
    }
    __syncthreads();

    for (int e = tid; e < NN * PW; e += 256) {
        const int i = e / PW, j = e % PW;
        if (j < NN) {
            const float a = 0.5f * (sG[i][j] + sG[j][i]);
            const float v = ((i == j) ? sdeg[i] : 0.0f) - a;
            sL[i][j] = sdinv[i] * sdinv[j] * v;
        } else {
            sL[i][j] = 0.0f;
        }
    }
    __syncthreads();

    lds_mm(sL, sL, sT2, 2.0f, nullptr, tid);   // T2 = 2 L^2
    __syncthreads();
    lds_mm(sL, sT2, sT3, 2.0f, sL, tid);       // T3 = 2 L T2 - L
    __syncthreads();

    lds_mm(sT2, sT2, sM, 0.25f, nullptr, tid); // L^4
    __syncthreads();
    lds_mm(sM, sM, sG, 1.0f, nullptr, tid);    // L^8
    __syncthreads();
    lds_mm(sG, sG, sM, 1.0f, nullptr, tid);    // L^16
    __syncthreads();
    lds_mm(sM, sM, sG, 1.0f, nullptr, tid);    // L^32
    __syncthreads();
    lds_mm(sG, sG, sM, 1.0f, nullptr, tid);    // L^64
    __syncthreads();

    if (tid < 64) {
        float lr[NN];
        #pragma unroll
        for (int j = 0; j < NN; ++j) lr[j] = (tid < NN) ? sM[tid][j] : 0.0f;
        unsigned h = (unsigned)(tid + 1) * 2654435761u;
        h ^= h >> 13; h *= 0x85ebca6bu; h ^= h >> 16;
        float v = (tid < NN) ? (0.25f + (float)(h & 1023) * (1.0f / 1024.0f)) : 0.0f;
        float n2 = v * v;
        #pragma unroll
        for (int off = 32; off > 0; off >>= 1) n2 += __shfl_xor(n2, off, 64);
        v *= rsqrtf(n2);
        float lam64 = 1.0f;
        #pragma unroll
        for (int it = 0; it < 4; ++it) {
            float acc = 0.f;
            #pragma unroll
            for (int j = 0; j < NN; ++j) acc = fmaf(lr[j], __shfl(v, j, 64), acc);
            float m2 = acc * acc;
            #pragma unroll
            for (int off = 32; off > 0; off >>= 1) m2 += __shfl_xor(m2, off, 64);
            lam64 = sqrtf(m2);
            v = acc * (1.0f / lam64);
        }
        if (tid == 0) slam64 = lam64;
    }
    __syncthreads();

    const float x = 0.15f * exp2f(log2f(slam64) * (1.0f / 64.0f));
    float iv[4];
    {
        const float xh = 0.5f * x, xh2 = xh * xh;
        #pragma unroll
        for (int n = 0; n < 4; ++n) {
            float c = 1.0f;
            for (int q = 2; q <= n; ++q) c /= (float)q;
            float p = 1.0f;
            for (int q = 0; q < n; ++q) p *= xh;
            float s = 0.f;
            for (int k = 0; k < 25; ++k) {
                s += c * p;
                p *= xh2;
                c /= (float)((k + 1) * (k + 1 + n));
            }
            iv[n] = s;
        }
    }
    const float ex = expf(x), emx = expf(-x);

    // Wn = l1norm(thresh(W)) -> sM
    {
        const float a1 = 2.f * ex * iv[1], a2 = 2.f * ex * iv[2], a3 = 2.f * ex * iv[3];
        for (int s = tid; s < NN * 11; s += 256) {
            const int i = s / 11, q = s % 11;
            const float4 l4  = *reinterpret_cast<const float4*>(&sL[i][q * 4]);
            const float4 t24 = *reinterpret_cast<const float4*>(&sT2[i][q * 4]);
            const float4 t34 = *reinterpret_cast<const float4*>(&sT3[i][q * 4]);
            float4 w;
            w.x = fmaf(a1, l4.x, fmaf(a2, t24.x, a3 * t34.x));
            w.y = fmaf(a1, l4.y, fmaf(a2, t24.y, a3 * t34.y));
            w.z = fmaf(a1, l4.z, fmaf(a2, t24.z, a3 * t34.z));
            w.w = fmaf(a1, l4.w, fmaf(a2, t24.w, a3 * t34.w));
            w.x = (w.x < 1e-4f) ? 0.f : w.x;  w.y = (w.y < 1e-4f) ? 0.f : w.y;
            w.z = (w.z < 1e-4f) ? 0.f : w.z;  w.w = (w.w < 1e-4f) ? 0.f : w.w;
            *reinterpret_cast<float4*>(&sM[i][q * 4]) = w;
        }
        __syncthreads();
        if (tid < NN) {
            float s = 0.f;
            #pragma unroll
            for (int q = 0; q < 11; ++q) {
                const float4 w4 = *reinterpret_cast<const float4*>(&sM[tid][q * 4]);
                s += fabsf(w4.x) + fabsf(w4.y) + fabsf(w4.z) + fabsf(w4.w);
            }
            srs[tid] = 1.0f / fmaxf(s, 1e-12f);
        }
        __syncthreads();
    }
    // scale Wn rows; Win = thresh(Wi) -> sG
    {
        const float a1 = -2.f * emx * iv[1], a2 = 2.f * emx * iv[2], a3 = -2.f * emx * iv[3];
        for (int s = tid; s < NN * 11; s += 256) {
            const int i = s / 11, q = s % 11;
            float4 m4 = *reinterpret_cast<float4*>(&sM[i][q * 4]);
            const float rs = srs[i];
            m4.x *= rs; m4.y *= rs; m4.z *= rs; m4.w *= rs;
            *reinterpret_cast<float4*>(&sM[i][q * 4]) = m4;
            const float4 l4  = *reinterpret_cast<const float4*>(&sL[i][q * 4]);
            const float4 t24 = *reinterpret_cast<const float4*>(&sT2[i][q * 4]);
            const float4 t34 = *reinterpret_cast<const float4*>(&sT3[i][q * 4]);
            float4 w;
            w.x = fmaf(a1, l4.x, fmaf(a2, t24.x, a3 * t34.x));
            w.y = fmaf(a1, l4.y, fmaf(a2, t24.y, a3 * t34.y));
            w.z = fmaf(a1, l4.z, fmaf(a2, t24.z, a3 * t34.z));
            w.w = fmaf(a1, l4.w, fmaf(a2, t24.w, a3 * t34.w));
            w.x = (w.x < 1e-4f) ? 0.f : w.x;  w.y = (w.y < 1e-4f) ? 0.f : w.y;
            w.z = (w.z < 1e-4f) ? 0.f : w.z;  w.w = (w.w < 1e-4f) ? 0.f : w.w;
            *reinterpret_cast<float4*>(&sG[i][q * 4]) = w;
        }
        __syncthreads();
        if (tid < NN) {
            float s = 0.f;
            #pragma unroll
            for (int q = 0; q < 11; ++q) {
                const float4 w4 = *reinterpret_cast<const float4*>(&sG[tid][q * 4]);
                s += fabsf(w4.x) + fabsf(w4.y) + fabsf(w4.z) + fabsf(w4.w);
            }
            sdeg[tid] = gk[tid] / fmaxf(s, 1e-12f);
        }
        __syncthreads();
        for (int s = tid; s < NN * 11; s += 256) {
            const int j = s / 11, q = s % 11;
            float4 w4 = *reinterpret_cast<float4*>(&sG[j][q * 4]);
            const float rs = sdeg[j];
            w4.x *= rs; w4.y *= rs; w4.z *= rs; w4.w *= rs;
            *reinterpret_cast<float4*>(&sG[j][q * 4]) = w4;
        }
        __syncthreads();
    }
    lds_mm(sM, sG, sL, 1.0f, nullptr, tid);   // M = Wn @ diag(gk) Win
    __syncthreads();
    float* dst = MT + (size_t)b * NN * NN;
    for (int e = tid; e < NN * NN; e += 256) {
        const int j = e / NN, i = e % NN;
        dst[e] = sL[i][j];
    }
}

// ---------------------------------------------------------------------------
// Prep: weights -> interleaved-split-swizzled Bint [3][288n][576], transposed
// ([n][k], zero-padded). Also coff = exp(lsv).
// ---------------------------------------------------------------------------
__global__ __launch_bounds__(256) void k_splitB(const float* __restrict__ gW,
                                                const float* __restrict__ W1,
                                                const float* __restrict__ W2,
                                                const float* __restrict__ lsv,
                                                unsigned short* __restrict__ Bint,
                                                float* __restrict__ coff)
{
    const int t = blockIdx.x * 256 + threadIdx.x;
    if (t < NN * DD) coff[t] = expf(lsv[t]);
    if (t >= 3 * DP * DP) return;
    const int w = t / (DP * DP);
    const int r = t % (DP * DP);
    const int n = r / DP, k = r % DP;
    const float* src = (w == 0) ? gW : ((w == 1) ? W1 : W2);
    const float v = (n < DD && k < DD) ? src[k * DD + n] : 0.0f;
    store_split(Bint + (size_t)w * WBE, n, k, v);
}

// ---------------------------------------------------------------------------
// K2: Y = M @ X per sample -> interleaved-split-swizzled Yint.
// ---------------------------------------------------------------------------
__global__ __launch_bounds__(320) void k_wavX(const float* __restrict__ MT,
                                              const float* __restrict__ X,
                                              unsigned short* __restrict__ Yint)
{
    const int b = blockIdx.x;
    const int c = threadIdx.x;
    const float* __restrict__ Mb = MT + (size_t)b * NN * NN;
    const bool rd = (c < DD);

    float out[NN];
    #pragma unroll
    for (int i = 0; i < NN; ++i) out[i] = 0.f;

    for (int j = 0; j < NN; ++j) {
        const float xj = rd ? X[((size_t)b * NN + j) * DD + c] : 0.0f;
        const float* __restrict__ Mrow = Mb + j * NN;   // uniform -> s_load
        #pragma unroll
        for (int i = 0; i < NN; ++i)
            out[i] = fmaf(Mrow[i], xj, out[i]);
    }

    if (c < DP) {
        #pragma unroll
        for (int i = 0; i < NN; ++i)
            store_split(Yint, (size_t)b * NN + i, c, out[i]);
    }
}

// ---------------------------------------------------------------------------
// Async 16B global -> LDS copy.
// ---------------------------------------------------------------------------
__device__ __forceinline__ void async16(const unsigned short* __restrict__ g,
                                        unsigned short* l)
{
    __builtin_amdgcn_global_load_lds(
        (const __attribute__((address_space(1))) unsigned int*)g,
        (__attribute__((address_space(3))) unsigned int*)l, 16, 0, 0);
}

// stage one (panel, kt32) tile: A 128x8 chunks + B 96x8 chunks, linear LDS.
__device__ __forceinline__ void stage_tile(const unsigned short* __restrict__ Ag,
                                           const unsigned short* __restrict__ Bg,
                                           unsigned short* As, unsigned short* Bs,
                                           long long row0, int panel, int kt32, int tid)
{
    const long long abase = row0 * AST + (long long)kt32 * 64;
    #pragma unroll
    for (int i = 0; i < 4; ++i) {
        const int cid = tid + i * 256;
        async16(Ag + abase + (long long)(cid >> 3) * AST + (cid & 7) * 8, As + cid * 8);
    }
    const long long bbase = (long long)(panel * 96) * AST + (long long)kt32 * 64;
    #pragma unroll
    for (int i = 0; i < 3; ++i) {
        const int cid = tid + i * 256;
        async16(Bg + bbase + (long long)(cid >> 3) * AST + (cid & 7) * 8, Bs + cid * 8);
    }
}

// ---------------------------------------------------------------------------
// K3: async-pipelined split-bf16 MFMA GEMM. C[M,288] = act(A @ B + ...).
// BM=128, 3 N-panels of 96 looped in-block, BK=32, double-buffered LDS,
// global_load_lds staging, XOR-swizzled chunks (T2), 2-phase schedule (T3min).
// OMODE: 0 = f32 out + bias; 1 = coff*relu split-interleaved out;
//        2 = relu(+bias) single-bf16 [m][DP] out.
// ---------------------------------------------------------------------------
template<int OMODE>
__global__ __launch_bounds__(256) void k_gemm2(
    const unsigned short* __restrict__ Aint,
    const unsigned short* __restrict__ Bint,
    const float* __restrict__ bias,
    const float* __restrict__ coff,
    float* __restrict__ outF,
    unsigned short* __restrict__ outU,
    unsigned short* __restrict__ outI)
{
    __shared__ __align__(16) unsigned short smem[2][(128 + 96) * 64];
    const int tid  = threadIdx.x;
    const int lane = tid & 63, w = tid >> 6;
    const int wr = w >> 1, wc = w & 1;
    const int lr = lane & 15, cb = lane >> 4;

    // bijective XCD-chunked swizzle (nwg is a multiple of 8 here, r=0 path ok)
    const int nwg = gridDim.x, orig = blockIdx.x;
    const int q = nwg >> 3, r = nwg & 7;
    const int xcd = orig & 7, loc = orig >> 3;
    const int bid = (xcd < r ? xcd * (q + 1) : r * (q + 1) + (xcd - r) * q) + loc;
    const long long row0 = (long long)bid * 128;

    f32x4 acc[4][3];
    #pragma unroll
    for (int mf = 0; mf < 4; ++mf)
        #pragma unroll
        for (int nf = 0; nf < 3; ++nf)
            acc[mf][nf] = (f32x4){0.f, 0.f, 0.f, 0.f};

    stage_tile(Aint, Bint, smem[0], smem[0] + 128 * 64, row0, 0, 0, tid);
    __syncthreads();   // implicit vmcnt(0) drain

    for (int t = 0; t < 27; ++t) {
        const int cur = t & 1;
        if (t < 26)
            stage_tile(Aint, Bint, smem[cur ^ 1], smem[cur ^ 1] + 128 * 64,
                       row0, (t + 1) / 9, (t + 1) % 9, tid);

        const unsigned short* As = smem[cur];
        const unsigned short* Bs = smem[cur] + 128 * 64;

        short8 ah[4], al[4];
        #pragma unroll
        for (int mf = 0; mf < 4; ++mf) {
            const int m = wr * 64 + mf * 16 + lr;
            const int sw = m & 7;
            ah[mf] = *reinterpret_cast<const short8*>(&As[m * 64 + ((cb ^ sw) << 3)]);
            al[mf] = *reinterpret_cast<const short8*>(&As[m * 64 + (((cb + 4) ^ sw) << 3)]);
        }
        #pragma unroll
        for (int nf = 0; nf < 3; ++nf) {
            const int n = wc * 48 + nf * 16 + lr;
            const int sw = n & 7;
            const short8 bh = *reinterpret_cast<const short8*>(&Bs[n * 64 + ((cb ^ sw) << 3)]);
            const short8 bl = *reinterpret_cast<const short8*>(&Bs[n * 64 + (((cb + 4) ^ sw) << 3)]);
            #pragma unroll
            for (int mf = 0; mf < 4; ++mf) {
                acc[mf][nf] = __builtin_amdgcn_mfma_f32_16x16x32_bf16(ah[mf], bh, acc[mf][nf], 0, 0, 0);
                acc[mf][nf] = __builtin_amdgcn_mfma_f32_16x16x32_bf16(al[mf], bh, acc[mf][nf], 0, 0, 0);
                acc[mf][nf] = __builtin_amdgcn_mfma_f32_16x16x32_bf16(ah[mf], bl, acc[mf][nf], 0, 0, 0);
            }
        }

        if ((t % 9) == 8) {       // end of panel p: epilogue + acc reset
            const int p = t / 9;
            #pragma unroll
            for (int mf = 0; mf < 4; ++mf) {
                const long long rb = row0 + wr * 64 + mf * 16 + ((lane >> 4) * 4);
                #pragma unroll
                for (int nf = 0; nf < 3; ++nf) {
                    const int col = p * 96 + wc * 48 + nf * 16 + lr;
                    const float bv = (OMODE != 1 && col < DD) ? bias[col] : 0.0f;
                    #pragma unroll
                    for (int rr = 0; rr < 4; ++rr) {
                        const long long row = rb + rr;
                        float v = acc[mf][nf][rr] + bv;
                        if (OMODE == 1) {
                            v = fmaxf(v, 0.f);
                            const float cf = (col < DD) ? coff[((unsigned)row % 41u) * DD + col] : 0.0f;
                            store_split(outI, row, col, v * cf);
                        } else if (OMODE == 2) {
                            outU[row * DP + col] = f2bf(fmaxf(v, 0.f));
                        } else {
                            outF[row * DP + col] = v;
                        }
                        acc[mf][nf][rr] = 0.f;
                    }
                }
            }
        }
        __syncthreads();   // drains this iter's async loads (vmcnt 0) + barrier
    }
}

// ---------------------------------------------------------------------------
// K5: per-sample node-mean of P2 (plain bf16) -> interleaved-split MPint.
// ---------------------------------------------------------------------------
__global__ __launch_bounds__(320) void k_meanP2(const unsigned short* __restrict__ P2,
                                                unsigned short* __restrict__ MPint)
{
    const int b = blockIdx.x;
    const int c = threadIdx.x;
    if (c >= DP) return;
    float s = 0.f;
    #pragma unroll
    for (int n = 0; n < NN; ++n)
        s += bf2f(P2[((size_t)b * NN + n) * DP + c]);
    s *= (1.0f / 41.0f);
    store_split(MPint, b, c, s);
}

// ---------------------------------------------------------------------------
__global__ __launch_bounds__(256) void k_stats(const float* __restrict__ seq, float* __restrict__ stats)
{
    __shared__ float s1[256], s2[256];
    const int d = blockIdx.x;
    float a = 0.f, q = 0.f;
    for (int b = threadIdx.x; b < BB; b += 256) {
        float v = seq[(size_t)b * DP + d];
        a += v; q = fmaf(v, v, q);
    }
    s1[threadIdx.x] = a; s2[threadIdx.x] = q;
    __syncthreads();
    for (int o = 128; o > 0; o >>= 1) {
        if (threadIdx.x < o) { s1[threadIdx.x] += s1[threadIdx.x + o]; s2[threadIdx.x] += s2[threadIdx.x + o]; }
        __syncthreads();
    }
    if (threadIdx.x == 0) {
        float m = s1[0] * (1.0f / BB);
        float v = s2[0] * (1.0f / BB) - m * m;
        stats[d]      = m;
        stats[DD + d] = 1.0f / sqrtf(v + 1e-5f);
    }
}

__global__ __launch_bounds__(256) void k_bn(const float* __restrict__ seq, const float* __restrict__ stats,
                                            const float* __restrict__ g, const float* __restrict__ bt,
                                            float* __restrict__ out)
{
    const long long idx = (long long)blockIdx.x * 256 + threadIdx.x;
    if (idx < (long long)BB * DD) {
        const int d = (int)(idx % DD);
        const long long b = idx / DD;
        out[idx] = (seq[b * DP + d] - stats[d]) * stats[DD + d] * g[d] + bt[d];
    }
}

// ---------------------------------------------------------------------------
extern "C" void kernel_launch(void* const* d_in, const int* in_sizes, int n_in,
                              void* d_out, int out_size, void* d_ws, size_t ws_size,
                              hipStream_t stream)
{
    const float* G   = (const float*)d_in[0];
    const float* X   = (const float*)d_in[1];
    const float* gk  = (const float*)d_in[2];
    const float* gW  = (const float*)d_in[3];
    const float* lsv = (const float*)d_in[4];
    const float* W1  = (const float*)d_in[5];
    const float* b1  = (const float*)d_in[6];
    const float* W2  = (const float*)d_in[7];
    const float* b2  = (const float*)d_in[8];
    const float* gam = (const float*)d_in[9];
    const float* bet = (const float*)d_in[10];

    char* p = (char*)d_ws;
    auto alloc = [&](size_t bytes) { void* r = (void*)p; p += (bytes + 255) & ~(size_t)255; return r; };
    float*          MT    = (float*)alloc((size_t)BB * NN * NN * 4);        // 27.5 MB
    unsigned short* Yint  = (unsigned short*)alloc((size_t)MROWS * AST * 2); // 193 MB
    unsigned short* Sint  = (unsigned short*)alloc((size_t)MROWS * AST * 2); // 193 MB
    unsigned short* P2    = (unsigned short*)alloc((size_t)MROWS * DP * 2);  // 97 MB
    unsigned short* Bint  = (unsigned short*)alloc((size_t)3 * WBE * 2);     // 1 MB
    unsigned short* MPint = (unsigned short*)alloc((size_t)BB * AST * 2);    // 4.7 MB
    float*          coff  = (float*)alloc((size_t)NN * DD * 4);
    float*          seqF  = (float*)alloc((size_t)BB * DP * 4);
    float*          stats = (float*)alloc(2 * DD * 4);

    k_wavelet<<<BB, 256, 0, stream>>>(G, gk, MT);
    k_splitB<<<(3 * DP * DP + 255) / 256, 256, 0, stream>>>(gW, W1, W2, lsv, Bint, coff);
    k_wavX<<<BB, 320, 0, stream>>>(MT, X, Yint);

    // GEMM1: S = coff * relu((M@X) @ gW)
    k_gemm2<1><<<(unsigned)(MROWS / 128), 256, 0, stream>>>(Yint, Bint, nullptr, coff,
                                                            nullptr, nullptr, Sint);
    // GEMM2: P2 = relu(S @ W1 + b1)
    k_gemm2<2><<<(unsigned)(MROWS / 128), 256, 0, stream>>>(Sint, Bint + WBE, b1, nullptr,
                                                            nullptr, P2, nullptr);
    // node-mean (commutes with W2)
    k_meanP2<<<BB, 320, 0, stream>>>(P2, MPint);
    // GEMM3: seq = mean(P2) @ W2 + b2
    k_gemm2<0><<<BB / 128, 256, 0, stream>>>(MPint, Bint + 2 * WBE, b2, nullptr,
                                             seqF, nullptr, nullptr);
    k_stats<<<DD, 256, 0, stream>>>(seqF, stats);
    k_bn<<<(unsigned)(((long long)BB * DD + 255) / 256), 256, 0, stream>>>(seqF, stats, gam, bet, (float*)d_out);
}